// Round 1
// baseline (2114.389 us; speedup 1.0000x reference)
//
#include <hip/hip_runtime.h>

#define IN_C   128
#define HC     128   // HEADS*OUT_C
#define HEADS  4
#define OUT_C  32
#define NEG    0.2f

// ---------------------------------------------------------------------------
// Pass A: xh = x @ W  [N,128]->[N,128], plus per-node logits
//   asrc[n,h] = sum_c xh[n,h,c]*att_src[h,c],  adst likewise.
// One wave per row; lane owns channels (2*lane, 2*lane+1); W staged in LDS.
// ---------------------------------------------------------------------------
__global__ __launch_bounds__(256) void gemm_logits_kernel(
    const float* __restrict__ x, const float* __restrict__ W,
    const float* __restrict__ att_src, const float* __restrict__ att_dst,
    float* __restrict__ xh, float* __restrict__ asrc, float* __restrict__ adst,
    int n)
{
    __shared__ float Wl[IN_C * HC];   // 64 KiB
    const int tid = threadIdx.x;
    for (int i = tid * 4; i < IN_C * HC; i += 256 * 4) {
        *(float4*)&Wl[i] = *(const float4*)&W[i];
    }
    __syncthreads();

    const int lane = tid & 63;
    const int wid  = tid >> 6;
    const int c0   = 2 * lane;        // global channel (h*32 + c)
    const int h    = lane >> 4;       // head 0..3

    const float as0 = att_src[h * OUT_C + (c0 & 31)];
    const float as1 = att_src[h * OUT_C + ((c0 & 31) + 1)];
    const float ad0 = att_dst[h * OUT_C + (c0 & 31)];
    const float ad1 = att_dst[h * OUT_C + ((c0 & 31) + 1)];

    const int stride = gridDim.x * 4;
    for (int r = blockIdx.x * 4 + wid; r < n; r += stride) {
        const float xr0 = x[(size_t)r * IN_C + lane];
        const float xr1 = x[(size_t)r * IN_C + 64 + lane];
        float acc0 = 0.f, acc1 = 0.f;
#pragma unroll
        for (int k = 0; k < 64; ++k) {
            const float xk = __shfl(xr0, k);
            const float2 w2 = *(const float2*)&Wl[k * HC + c0];
            acc0 = fmaf(xk, w2.x, acc0);
            acc1 = fmaf(xk, w2.y, acc1);
        }
#pragma unroll
        for (int k = 0; k < 64; ++k) {
            const float xk = __shfl(xr1, k);
            const float2 w2 = *(const float2*)&Wl[(k + 64) * HC + c0];
            acc0 = fmaf(xk, w2.x, acc0);
            acc1 = fmaf(xk, w2.y, acc1);
        }
        *(float2*)&xh[(size_t)r * HC + c0] = make_float2(acc0, acc1);

        // per-head (16-lane group) reduction for logits
        float ps = acc0 * as0 + acc1 * as1;
        float pd = acc0 * ad0 + acc1 * ad1;
#pragma unroll
        for (int m = 1; m < 16; m <<= 1) {
            ps += __shfl_xor(ps, m);
            pd += __shfl_xor(pd, m);
        }
        if ((lane & 15) == 0) {
            asrc[(size_t)r * HEADS + h] = ps;
            adst[(size_t)r * HEADS + h] = pd;
        }
    }
}

// ---------------------------------------------------------------------------
// Pass B: per-edge softmax denominators  s[dst,h] += exp(lrelu(asrc+adst))
// ---------------------------------------------------------------------------
__global__ __launch_bounds__(256) void edge_sums_kernel(
    const int* __restrict__ src, const int* __restrict__ dst,
    const float* __restrict__ asrc, const float* __restrict__ adst,
    float* __restrict__ s, int E)
{
    const int t = blockIdx.x * 256 + threadIdx.x;
    if (t >= E) return;
    const int si = src[t];
    const int di = dst[t];
    const float4 a4 = *(const float4*)&asrc[(size_t)si * 4];
    const float4 b4 = *(const float4*)&adst[(size_t)di * 4];
    float z;
    z = a4.x + b4.x; atomicAdd(&s[(size_t)di * 4 + 0], __expf(z > 0.f ? z : NEG * z));
    z = a4.y + b4.y; atomicAdd(&s[(size_t)di * 4 + 1], __expf(z > 0.f ? z : NEG * z));
    z = a4.z + b4.z; atomicAdd(&s[(size_t)di * 4 + 2], __expf(z > 0.f ? z : NEG * z));
    z = a4.w + b4.w; atomicAdd(&s[(size_t)di * 4 + 3], __expf(z > 0.f ? z : NEG * z));
}

// ---------------------------------------------------------------------------
// Pass C: unnormalized aggregation  acc[dst,c] += w(e,h) * xh[src,c]
// One wave per edge; lane owns a float2 of channels.
// ---------------------------------------------------------------------------
__global__ __launch_bounds__(256) void aggregate_kernel(
    const int* __restrict__ src, const int* __restrict__ dst,
    const float* __restrict__ asrc, const float* __restrict__ adst,
    const float* __restrict__ xh, float* __restrict__ acc, int E)
{
    const int eid = blockIdx.x * 4 + (threadIdx.x >> 6);
    if (eid >= E) return;
    const int lane = threadIdx.x & 63;
    const int si = src[eid];
    const int di = dst[eid];
    const int h  = lane >> 4;
    const float a = asrc[(size_t)si * 4 + h] + adst[(size_t)di * 4 + h];
    const float w = __expf(a > 0.f ? a : NEG * a);
    const float2 xv = *(const float2*)&xh[(size_t)si * HC + 2 * lane];
    atomicAdd(&acc[(size_t)di * HC + 2 * lane + 0], w * xv.x);
    atomicAdd(&acc[(size_t)di * HC + 2 * lane + 1], w * xv.y);
}

// ---------------------------------------------------------------------------
// Pass D: finalize — add self-loop, normalize, bias, relu.  In-place on d_out.
// One wave per node; lane owns a float2 of channels.
// ---------------------------------------------------------------------------
__global__ __launch_bounds__(256) void finalize_kernel(
    const float* __restrict__ asrc, const float* __restrict__ adst,
    const float* __restrict__ s, const float* __restrict__ xh,
    const float* __restrict__ bias, float* __restrict__ out, int n)
{
    const int r = blockIdx.x * 4 + (threadIdx.x >> 6);
    if (r >= n) return;
    const int lane = threadIdx.x & 63;
    const int h = lane >> 4;
    const int c = 2 * lane;
    const float a = asrc[(size_t)r * 4 + h] + adst[(size_t)r * 4 + h];
    const float wself = __expf(a > 0.f ? a : NEG * a);
    const float sv = s[(size_t)r * 4 + h] + wself;
    const float inv = 1.f / sv;
    const float2 xv = *(const float2*)&xh[(size_t)r * HC + c];
    const float2 ac = *(const float2*)&out[(size_t)r * HC + c];
    const float2 b2 = *(const float2*)&bias[c];
    float r0 = (ac.x + wself * xv.x) * inv + b2.x;
    float r1 = (ac.y + wself * xv.y) * inv + b2.y;
    out[(size_t)r * HC + c + 0] = r0 > 0.f ? r0 : 0.f;
    out[(size_t)r * HC + c + 1] = r1 > 0.f ? r1 : 0.f;
}

// ---------------------------------------------------------------------------
extern "C" void kernel_launch(void* const* d_in, const int* in_sizes, int n_in,
                              void* d_out, int out_size, void* d_ws, size_t ws_size,
                              hipStream_t stream)
{
    const float* x       = (const float*)d_in[0];
    const int*   ei      = (const int*)d_in[1];   // [2,E] flat: src then dst
    const float* W       = (const float*)d_in[2];
    const float* att_src = (const float*)d_in[3];
    const float* att_dst = (const float*)d_in[4];
    const float* bias    = (const float*)d_in[5];

    const int n = in_sizes[0] / IN_C;
    const int E = in_sizes[1] / 2;

    float* out  = (float*)d_out;
    float* xh   = (float*)d_ws;                          // n*128 f32
    float* asrc = xh   + (size_t)n * HC;                 // n*4
    float* adst = asrc + (size_t)n * HEADS;              // n*4
    float* s    = adst + (size_t)n * HEADS;              // n*4

    hipMemsetAsync(s, 0, (size_t)n * HEADS * sizeof(float), stream);
    hipMemsetAsync(d_out, 0, (size_t)out_size * sizeof(float), stream);

    gemm_logits_kernel<<<512, 256, 0, stream>>>(x, W, att_src, att_dst,
                                                xh, asrc, adst, n);
    edge_sums_kernel<<<(E + 255) / 256, 256, 0, stream>>>(ei, ei + E,
                                                          asrc, adst, s, E);
    aggregate_kernel<<<(E + 3) / 4, 256, 0, stream>>>(ei, ei + E, asrc, adst,
                                                      xh, out, E);
    finalize_kernel<<<(n + 3) / 4, 256, 0, stream>>>(asrc, adst, s, xh,
                                                     bias, out, n);
}

// Round 2
// 832.951 us; speedup vs baseline: 2.5384x; 2.5384x over previous
//
#include <hip/hip_runtime.h>

#define IN_C   128
#define HC     128   // HEADS*OUT_C
#define HEADS  4
#define OUT_C  32
#define NEG    0.2f

// ---------------------------------------------------------------------------
// Pass A: xh = x @ W  [N,128]->[N,128], plus per-node logits
//   asrc[n,h] = sum_c xh[n,h,c]*att_src[h,c],  adst likewise.
// One wave per row; lane owns channels (2*lane, 2*lane+1); W staged in LDS.
// ---------------------------------------------------------------------------
__global__ __launch_bounds__(256) void gemm_logits_kernel(
    const float* __restrict__ x, const float* __restrict__ W,
    const float* __restrict__ att_src, const float* __restrict__ att_dst,
    float* __restrict__ xh, float* __restrict__ asrc, float* __restrict__ adst,
    int n)
{
    __shared__ float Wl[IN_C * HC];   // 64 KiB
    const int tid = threadIdx.x;
    for (int i = tid * 4; i < IN_C * HC; i += 256 * 4) {
        *(float4*)&Wl[i] = *(const float4*)&W[i];
    }
    __syncthreads();

    const int lane = tid & 63;
    const int wid  = tid >> 6;
    const int c0   = 2 * lane;        // global channel (h*32 + c)
    const int h    = lane >> 4;       // head 0..3

    const float as0 = att_src[h * OUT_C + (c0 & 31)];
    const float as1 = att_src[h * OUT_C + ((c0 & 31) + 1)];
    const float ad0 = att_dst[h * OUT_C + (c0 & 31)];
    const float ad1 = att_dst[h * OUT_C + ((c0 & 31) + 1)];

    const int stride = gridDim.x * 4;
    for (int r = blockIdx.x * 4 + wid; r < n; r += stride) {
        const float xr0 = x[(size_t)r * IN_C + lane];
        const float xr1 = x[(size_t)r * IN_C + 64 + lane];
        float acc0 = 0.f, acc1 = 0.f;
#pragma unroll
        for (int k = 0; k < 64; ++k) {
            const float xk = __shfl(xr0, k);
            const float2 w2 = *(const float2*)&Wl[k * HC + c0];
            acc0 = fmaf(xk, w2.x, acc0);
            acc1 = fmaf(xk, w2.y, acc1);
        }
#pragma unroll
        for (int k = 0; k < 64; ++k) {
            const float xk = __shfl(xr1, k);
            const float2 w2 = *(const float2*)&Wl[(k + 64) * HC + c0];
            acc0 = fmaf(xk, w2.x, acc0);
            acc1 = fmaf(xk, w2.y, acc1);
        }
        *(float2*)&xh[(size_t)r * HC + c0] = make_float2(acc0, acc1);

        // per-head (16-lane group) reduction for logits
        float ps = acc0 * as0 + acc1 * as1;
        float pd = acc0 * ad0 + acc1 * ad1;
#pragma unroll
        for (int m = 1; m < 16; m <<= 1) {
            ps += __shfl_xor(ps, m);
            pd += __shfl_xor(pd, m);
        }
        if ((lane & 15) == 0) {
            asrc[(size_t)r * HEADS + h] = ps;
            adst[(size_t)r * HEADS + h] = pd;
        }
    }
}

// ---------------------------------------------------------------------------
// CSR build: histogram of dst degrees
// ---------------------------------------------------------------------------
__global__ __launch_bounds__(256) void hist_kernel(
    const int* __restrict__ dst, int* __restrict__ deg, int E)
{
    const int t = blockIdx.x * 256 + threadIdx.x;
    if (t >= E) return;
    atomicAdd(&deg[dst[t]], 1);
}

// ---------------------------------------------------------------------------
// Exclusive scan over deg[n] -> cursor[n]  (3-kernel standard scan)
// scan1: per-block (1024 elems) exclusive scan + block sum
// ---------------------------------------------------------------------------
__global__ __launch_bounds__(256) void scan1_kernel(
    const int* __restrict__ deg, int* __restrict__ cursor,
    int* __restrict__ bsum, int n)
{
    __shared__ int sd[256];
    const int t   = threadIdx.x;
    const int idx = blockIdx.x * 1024 + t * 4;

    int4 v = make_int4(0, 0, 0, 0);
    if (idx + 3 < n) {
        v = *(const int4*)&deg[idx];
    } else {
        if (idx     < n) v.x = deg[idx];
        if (idx + 1 < n) v.y = deg[idx + 1];
        if (idx + 2 < n) v.z = deg[idx + 2];
        if (idx + 3 < n) v.w = deg[idx + 3];
    }
    const int s0 = v.x, s1 = s0 + v.y, s2 = s1 + v.z, s3 = s2 + v.w;
    sd[t] = s3;
    __syncthreads();
#pragma unroll
    for (int off = 1; off < 256; off <<= 1) {
        const int val = (t >= off) ? sd[t - off] : 0;
        __syncthreads();
        sd[t] += val;
        __syncthreads();
    }
    const int texcl = (t > 0) ? sd[t - 1] : 0;
    if (t == 255) bsum[blockIdx.x] = sd[255];

    int4 o;
    o.x = texcl; o.y = texcl + s0; o.z = texcl + s1; o.w = texcl + s2;
    if (idx + 3 < n) {
        *(int4*)&cursor[idx] = o;
    } else {
        if (idx     < n) cursor[idx]     = o.x;
        if (idx + 1 < n) cursor[idx + 1] = o.y;
        if (idx + 2 < n) cursor[idx + 2] = o.z;
        if (idx + 3 < n) cursor[idx + 3] = o.w;
    }
}

// scan2: exclusive scan of block sums (single block; B <= 256 for n <= 262144)
__global__ __launch_bounds__(256) void scan2_kernel(int* __restrict__ bsum, int B)
{
    __shared__ int sd[256];
    const int t = threadIdx.x;
    sd[t] = (t < B) ? bsum[t] : 0;
    __syncthreads();
#pragma unroll
    for (int off = 1; off < 256; off <<= 1) {
        const int val = (t >= off) ? sd[t - off] : 0;
        __syncthreads();
        sd[t] += val;
        __syncthreads();
    }
    if (t < B) bsum[t] = (t > 0) ? sd[t - 1] : 0;
    __syncthreads();
}

// scan3: add scanned block sums back
__global__ __launch_bounds__(256) void scan3_kernel(
    int* __restrict__ cursor, const int* __restrict__ bsum, int n)
{
    const int idx = (blockIdx.x * 256 + threadIdx.x) * 4;
    if (idx >= n) return;
    const int add = bsum[idx >> 10];
    if (add == 0) return;
    if (idx + 3 < n) {
        int4 v = *(int4*)&cursor[idx];
        v.x += add; v.y += add; v.z += add; v.w += add;
        *(int4*)&cursor[idx] = v;
    } else {
        if (idx     < n) cursor[idx]     += add;
        if (idx + 1 < n) cursor[idx + 1] += add;
        if (idx + 2 < n) cursor[idx + 2] += add;
        if (idx + 3 < n) cursor[idx + 3] += add;
    }
}

// ---------------------------------------------------------------------------
// Scatter edges into CSR slots. After this, cursor[i] == end offset of node i.
// ---------------------------------------------------------------------------
__global__ __launch_bounds__(256) void scatter_kernel(
    const int* __restrict__ src, const int* __restrict__ dst,
    int* __restrict__ cursor, int* __restrict__ csr_src, int E)
{
    const int t = blockIdx.x * 256 + threadIdx.x;
    if (t >= E) return;
    const int slot = atomicAdd(&cursor[dst[t]], 1);
    csr_src[slot] = src[t];
}

// ---------------------------------------------------------------------------
// Fused aggregate: one wave per dst node. Registers accumulate the weighted
// sum AND the softmax denominator; self-loop folded in; normalize+bias+relu
// and a single 512B output write. Zero atomics.
// ---------------------------------------------------------------------------
__global__ __launch_bounds__(256) void aggregate_csr_kernel(
    const int* __restrict__ csr_src, const int* __restrict__ cursor,
    const int* __restrict__ deg,
    const float* __restrict__ asrc, const float* __restrict__ adst,
    const float* __restrict__ xh, const float* __restrict__ bias,
    float* __restrict__ out, int n)
{
    const int node = blockIdx.x * 4 + (threadIdx.x >> 6);
    if (node >= n) return;
    const int lane = threadIdx.x & 63;
    const int h    = lane >> 4;
    const int c0   = 2 * lane;

    const int end = cursor[node];          // post-scatter == end offset
    const int d   = deg[node];
    const int beg = end - d;

    const float adh = adst[(size_t)node * 4 + h];

    // self-loop contribution
    float a = asrc[(size_t)node * 4 + h] + adh;
    float w = __expf(a > 0.f ? a : NEG * a);
    const float2 xself = *(const float2*)&xh[(size_t)node * HC + c0];
    float acc0 = w * xself.x;
    float acc1 = w * xself.y;
    float ssum = w;

    // 1-ahead prefetch of the (wave-uniform) source index
    int s = (beg < end) ? csr_src[beg] : 0;
    for (int e = beg; e < end; ++e) {
        const int snext = (e + 1 < end) ? csr_src[e + 1] : 0;
        const float a2 = asrc[(size_t)s * 4 + h] + adh;
        const float w2 = __expf(a2 > 0.f ? a2 : NEG * a2);
        const float2 xv = *(const float2*)&xh[(size_t)s * HC + c0];
        acc0 = fmaf(w2, xv.x, acc0);
        acc1 = fmaf(w2, xv.y, acc1);
        ssum += w2;
        s = snext;
    }

    const float inv = 1.f / ssum;
    const float2 b2 = *(const float2*)&bias[c0];
    float r0 = acc0 * inv + b2.x;
    float r1 = acc1 * inv + b2.y;
    *(float2*)&out[(size_t)node * HC + c0] =
        make_float2(r0 > 0.f ? r0 : 0.f, r1 > 0.f ? r1 : 0.f);
}

// ---------------------------------------------------------------------------
extern "C" void kernel_launch(void* const* d_in, const int* in_sizes, int n_in,
                              void* d_out, int out_size, void* d_ws, size_t ws_size,
                              hipStream_t stream)
{
    const float* x       = (const float*)d_in[0];
    const int*   ei      = (const int*)d_in[1];   // [2,E] flat: src then dst
    const float* W       = (const float*)d_in[2];
    const float* att_src = (const float*)d_in[3];
    const float* att_dst = (const float*)d_in[4];
    const float* bias    = (const float*)d_in[5];

    const int n = in_sizes[0] / IN_C;
    const int E = in_sizes[1] / 2;
    const int* src = ei;
    const int* dst = ei + E;

    float* out  = (float*)d_out;

    // workspace layout
    float* xh      = (float*)d_ws;                        // n*128 f32 (51.2MB)
    float* asrc    = xh   + (size_t)n * HC;               // n*4
    float* adst    = asrc + (size_t)n * HEADS;            // n*4
    int*   deg     = (int*)(adst + (size_t)n * HEADS);    // n
    int*   cursor  = deg + n;                             // n
    int*   bsum    = cursor + n;                          // 256
    int*   csr_src = bsum + 256;                          // E

    hipMemsetAsync(deg, 0, (size_t)n * sizeof(int), stream);

    gemm_logits_kernel<<<512, 256, 0, stream>>>(x, W, att_src, att_dst,
                                                xh, asrc, adst, n);

    const int B = (n + 1023) / 1024;   // n<=262144 -> B<=256 (scan2 single block)
    hist_kernel<<<(E + 255) / 256, 256, 0, stream>>>(dst, deg, E);
    scan1_kernel<<<B, 256, 0, stream>>>(deg, cursor, bsum, n);
    scan2_kernel<<<1, 256, 0, stream>>>(bsum, B);
    scan3_kernel<<<B, 256, 0, stream>>>(cursor, bsum, n);
    scatter_kernel<<<(E + 255) / 256, 256, 0, stream>>>(src, dst, cursor,
                                                        csr_src, E);
    aggregate_csr_kernel<<<(n + 3) / 4, 256, 0, stream>>>(csr_src, cursor, deg,
                                                          asrc, adst, xh, bias,
                                                          out, n);
}

// Round 3
// 416.315 us; speedup vs baseline: 5.0788x; 2.0008x over previous
//
#include <hip/hip_runtime.h>

#define IN_C   128
#define HC     128   // HEADS*OUT_C
#define HEADS  4
#define OUT_C  32
#define NEG    0.2f
#define BM     64    // rows per block in GEMM

// ---------------------------------------------------------------------------
// Pass A: xh = x @ W  [N,128]->[N,128], plus per-node logits.
// Block = 256 threads, 64 rows. Thread (tx,ty) owns rows ty*4..+3 and cols
// {tx*4..+3} U {64+tx*4..+3}  (two quads -> 2-way LDS bank aliasing = free).
// W staged once in LDS [k][c]; x read from global with 16-lane broadcast.
// 32 FMA per 2 ds_read_b128 -- VALU/LDS balanced.
// ---------------------------------------------------------------------------
__global__ __launch_bounds__(256) void gemm_logits_kernel(
    const float* __restrict__ x, const float* __restrict__ W,
    const float* __restrict__ att_src, const float* __restrict__ att_dst,
    float* __restrict__ xh, float* __restrict__ asrc, float* __restrict__ adst,
    int n)
{
    __shared__ float Wl[IN_C * HC];   // 64 KiB
    const int tid = threadIdx.x;
#pragma unroll
    for (int i = 0; i < 16; ++i) {
        const int idx = (i * 256 + tid) * 4;
        *(float4*)&Wl[idx] = *(const float4*)&W[idx];
    }

    const int tx   = tid & 15;
    const int ty   = tid >> 4;
    const int c0   = tx * 4;
    const int row0 = blockIdx.x * BM + ty * 4;

    __syncthreads();

    float acc[4][8];
#pragma unroll
    for (int r = 0; r < 4; ++r)
#pragma unroll
        for (int j = 0; j < 8; ++j) acc[r][j] = 0.f;

    float4 xq[4];
#pragma unroll
    for (int r = 0; r < 4; ++r)
        xq[r] = (row0 + r < n) ? *(const float4*)&x[(size_t)(row0 + r) * IN_C]
                               : make_float4(0.f, 0.f, 0.f, 0.f);

    for (int kc = 0; kc < 32; ++kc) {
        const int k = kc * 4;
        float4 xn[4];
#pragma unroll
        for (int r = 0; r < 4; ++r)
            xn[r] = (kc < 31 && row0 + r < n)
                  ? *(const float4*)&x[(size_t)(row0 + r) * IN_C + k + 4]
                  : make_float4(0.f, 0.f, 0.f, 0.f);
#pragma unroll
        for (int kk = 0; kk < 4; ++kk) {
            const float4 w0 = *(const float4*)&Wl[(k + kk) * HC + c0];
            const float4 w1 = *(const float4*)&Wl[(k + kk) * HC + c0 + 64];
#pragma unroll
            for (int r = 0; r < 4; ++r) {
                const float xv = ((const float*)&xq[r])[kk];
                acc[r][0] = fmaf(xv, w0.x, acc[r][0]);
                acc[r][1] = fmaf(xv, w0.y, acc[r][1]);
                acc[r][2] = fmaf(xv, w0.z, acc[r][2]);
                acc[r][3] = fmaf(xv, w0.w, acc[r][3]);
                acc[r][4] = fmaf(xv, w1.x, acc[r][4]);
                acc[r][5] = fmaf(xv, w1.y, acc[r][5]);
                acc[r][6] = fmaf(xv, w1.z, acc[r][6]);
                acc[r][7] = fmaf(xv, w1.w, acc[r][7]);
            }
        }
#pragma unroll
        for (int r = 0; r < 4; ++r) xq[r] = xn[r];
    }

    // store xh
#pragma unroll
    for (int r = 0; r < 4; ++r) {
        const int row = row0 + r;
        if (row < n) {
            *(float4*)&xh[(size_t)row * HC + c0] =
                make_float4(acc[r][0], acc[r][1], acc[r][2], acc[r][3]);
            *(float4*)&xh[(size_t)row * HC + c0 + 64] =
                make_float4(acc[r][4], acc[r][5], acc[r][6], acc[r][7]);
        }
    }

    // logits: cols c0..c0+3 are in head tx>>3; cols 64+c0.. are in head 2+(tx>>3)
    const float4 as0 = *(const float4*)&att_src[c0];
    const float4 as1 = *(const float4*)&att_src[c0 + 64];
    const float4 ad0 = *(const float4*)&att_dst[c0];
    const float4 ad1 = *(const float4*)&att_dst[c0 + 64];
#pragma unroll
    for (int r = 0; r < 4; ++r) {
        float p0 = acc[r][0]*as0.x + acc[r][1]*as0.y + acc[r][2]*as0.z + acc[r][3]*as0.w;
        float p1 = acc[r][4]*as1.x + acc[r][5]*as1.y + acc[r][6]*as1.z + acc[r][7]*as1.w;
        float q0 = acc[r][0]*ad0.x + acc[r][1]*ad0.y + acc[r][2]*ad0.z + acc[r][3]*ad0.w;
        float q1 = acc[r][4]*ad1.x + acc[r][5]*ad1.y + acc[r][6]*ad1.z + acc[r][7]*ad1.w;
#pragma unroll
        for (int m = 1; m < 8; m <<= 1) {
            p0 += __shfl_xor(p0, m);
            p1 += __shfl_xor(p1, m);
            q0 += __shfl_xor(q0, m);
            q1 += __shfl_xor(q1, m);
        }
        const int row = row0 + r;
        if ((tx & 7) == 0 && row < n) {
            const int h = tx >> 3;
            asrc[(size_t)row * 4 + h]     = p0;
            asrc[(size_t)row * 4 + 2 + h] = p1;
            adst[(size_t)row * 4 + h]     = q0;
            adst[(size_t)row * 4 + 2 + h] = q1;
        }
    }
}

// ---------------------------------------------------------------------------
// CSR build: histogram of dst degrees
// ---------------------------------------------------------------------------
__global__ __launch_bounds__(256) void hist_kernel(
    const int* __restrict__ dst, int* __restrict__ deg, int E)
{
    const int t = blockIdx.x * 256 + threadIdx.x;
    if (t >= E) return;
    atomicAdd(&deg[dst[t]], 1);
}

// ---------------------------------------------------------------------------
// Exclusive scan over deg[n] -> cursor[n]
// ---------------------------------------------------------------------------
__global__ __launch_bounds__(256) void scan1_kernel(
    const int* __restrict__ deg, int* __restrict__ cursor,
    int* __restrict__ bsum, int n)
{
    __shared__ int sd[256];
    const int t   = threadIdx.x;
    const int idx = blockIdx.x * 1024 + t * 4;

    int4 v = make_int4(0, 0, 0, 0);
    if (idx + 3 < n) {
        v = *(const int4*)&deg[idx];
    } else {
        if (idx     < n) v.x = deg[idx];
        if (idx + 1 < n) v.y = deg[idx + 1];
        if (idx + 2 < n) v.z = deg[idx + 2];
        if (idx + 3 < n) v.w = deg[idx + 3];
    }
    const int s0 = v.x, s1 = s0 + v.y, s2 = s1 + v.z, s3 = s2 + v.w;
    sd[t] = s3;
    __syncthreads();
#pragma unroll
    for (int off = 1; off < 256; off <<= 1) {
        const int val = (t >= off) ? sd[t - off] : 0;
        __syncthreads();
        sd[t] += val;
        __syncthreads();
    }
    const int texcl = (t > 0) ? sd[t - 1] : 0;
    if (t == 255) bsum[blockIdx.x] = sd[255];

    int4 o;
    o.x = texcl; o.y = texcl + s0; o.z = texcl + s1; o.w = texcl + s2;
    if (idx + 3 < n) {
        *(int4*)&cursor[idx] = o;
    } else {
        if (idx     < n) cursor[idx]     = o.x;
        if (idx + 1 < n) cursor[idx + 1] = o.y;
        if (idx + 2 < n) cursor[idx + 2] = o.z;
        if (idx + 3 < n) cursor[idx + 3] = o.w;
    }
}

__global__ __launch_bounds__(256) void scan2_kernel(int* __restrict__ bsum, int B)
{
    __shared__ int sd[256];
    const int t = threadIdx.x;
    sd[t] = (t < B) ? bsum[t] : 0;
    __syncthreads();
#pragma unroll
    for (int off = 1; off < 256; off <<= 1) {
        const int val = (t >= off) ? sd[t - off] : 0;
        __syncthreads();
        sd[t] += val;
        __syncthreads();
    }
    if (t < B) bsum[t] = (t > 0) ? sd[t - 1] : 0;
}

__global__ __launch_bounds__(256) void scan3_kernel(
    int* __restrict__ cursor, const int* __restrict__ bsum, int n)
{
    const int idx = (blockIdx.x * 256 + threadIdx.x) * 4;
    if (idx >= n) return;
    const int add = bsum[idx >> 10];
    if (add == 0) return;
    if (idx + 3 < n) {
        int4 v = *(int4*)&cursor[idx];
        v.x += add; v.y += add; v.z += add; v.w += add;
        *(int4*)&cursor[idx] = v;
    } else {
        if (idx     < n) cursor[idx]     += add;
        if (idx + 1 < n) cursor[idx + 1] += add;
        if (idx + 2 < n) cursor[idx + 2] += add;
        if (idx + 3 < n) cursor[idx + 3] += add;
    }
}

// ---------------------------------------------------------------------------
// Scatter edges into CSR slots. After this, cursor[i] == end offset of node i.
// ---------------------------------------------------------------------------
__global__ __launch_bounds__(256) void scatter_kernel(
    const int* __restrict__ src, const int* __restrict__ dst,
    int* __restrict__ cursor, int* __restrict__ csr_src, int E)
{
    const int t = blockIdx.x * 256 + threadIdx.x;
    if (t >= E) return;
    const int slot = atomicAdd(&cursor[dst[t]], 1);
    csr_src[slot] = src[t];
}

// ---------------------------------------------------------------------------
// Fused aggregate: one wave per dst node. Software-pipelined gathers:
// index 2-ahead, data (asrc + xh) 1-ahead. All pipeline conditions are
// wave-uniform (node is wave-uniform) -> no divergence.
// ---------------------------------------------------------------------------
__global__ __launch_bounds__(256) void aggregate_csr_kernel(
    const int* __restrict__ csr_src, const int* __restrict__ cursor,
    const int* __restrict__ deg,
    const float* __restrict__ asrc, const float* __restrict__ adst,
    const float* __restrict__ xh, const float* __restrict__ bias,
    float* __restrict__ out, int n)
{
    const int node = blockIdx.x * 4 + (threadIdx.x >> 6);
    if (node >= n) return;
    const int lane = threadIdx.x & 63;
    const int h    = lane >> 4;
    const int c0   = 2 * lane;

    const int end = cursor[node];          // post-scatter == end offset
    const int beg = end - deg[node];

    const float adh = adst[(size_t)node * 4 + h];

    // self-loop contribution
    float a = asrc[(size_t)node * 4 + h] + adh;
    float w = __expf(a > 0.f ? a : NEG * a);
    const float2 xself = *(const float2*)&xh[(size_t)node * HC + c0];
    float acc0 = w * xself.x;
    float acc1 = w * xself.y;
    float ssum = w;

    int    s1 = (beg + 1 < end) ? csr_src[beg + 1] : 0;
    float  a0 = 0.f;
    float2 x0 = make_float2(0.f, 0.f);
    if (beg < end) {
        const int s0 = csr_src[beg];
        a0 = asrc[(size_t)s0 * 4 + h];
        x0 = *(const float2*)&xh[(size_t)s0 * HC + c0];
    }

    for (int e = beg; e < end; ++e) {
        const int    s2 = (e + 2 < end) ? csr_src[e + 2] : 0;
        const float  a1 = (e + 1 < end) ? asrc[(size_t)s1 * 4 + h] : 0.f;
        const float2 x1 = (e + 1 < end) ? *(const float2*)&xh[(size_t)s1 * HC + c0]
                                        : make_float2(0.f, 0.f);
        const float z  = a0 + adh;
        const float w2 = __expf(z > 0.f ? z : NEG * z);
        acc0 = fmaf(w2, x0.x, acc0);
        acc1 = fmaf(w2, x0.y, acc1);
        ssum += w2;
        s1 = s2; a0 = a1; x0 = x1;
    }

    const float inv = 1.f / ssum;
    const float2 b2 = *(const float2*)&bias[c0];
    float r0 = acc0 * inv + b2.x;
    float r1 = acc1 * inv + b2.y;
    *(float2*)&out[(size_t)node * HC + c0] =
        make_float2(r0 > 0.f ? r0 : 0.f, r1 > 0.f ? r1 : 0.f);
}

// ---------------------------------------------------------------------------
extern "C" void kernel_launch(void* const* d_in, const int* in_sizes, int n_in,
                              void* d_out, int out_size, void* d_ws, size_t ws_size,
                              hipStream_t stream)
{
    const float* x       = (const float*)d_in[0];
    const int*   ei      = (const int*)d_in[1];   // [2,E] flat: src then dst
    const float* W       = (const float*)d_in[2];
    const float* att_src = (const float*)d_in[3];
    const float* att_dst = (const float*)d_in[4];
    const float* bias    = (const float*)d_in[5];

    const int n = in_sizes[0] / IN_C;
    const int E = in_sizes[1] / 2;
    const int* src = ei;
    const int* dst = ei + E;

    float* out  = (float*)d_out;

    // workspace layout
    float* xh      = (float*)d_ws;                        // n*128 f32 (51.2MB)
    float* asrc    = xh   + (size_t)n * HC;               // n*4
    float* adst    = asrc + (size_t)n * HEADS;            // n*4
    int*   deg     = (int*)(adst + (size_t)n * HEADS);    // n
    int*   cursor  = deg + n;                             // n
    int*   bsum    = cursor + n;                          // 256
    int*   csr_src = bsum + 256;                          // E

    hipMemsetAsync(deg, 0, (size_t)n * sizeof(int), stream);

    gemm_logits_kernel<<<(n + BM - 1) / BM, 256, 0, stream>>>(
        x, W, att_src, att_dst, xh, asrc, adst, n);

    const int B = (n + 1023) / 1024;   // n<=262144 -> B<=256 (scan2 single block)
    hist_kernel<<<(E + 255) / 256, 256, 0, stream>>>(dst, deg, E);
    scan1_kernel<<<B, 256, 0, stream>>>(deg, cursor, bsum, n);
    scan2_kernel<<<1, 256, 0, stream>>>(bsum, B);
    scan3_kernel<<<B, 256, 0, stream>>>(cursor, bsum, n);
    scatter_kernel<<<(E + 255) / 256, 256, 0, stream>>>(src, dst, cursor,
                                                        csr_src, E);
    aggregate_csr_kernel<<<(n + 3) / 4, 256, 0, stream>>>(csr_src, cursor, deg,
                                                          asrc, adst, xh, bias,
                                                          out, n);
}

// Round 4
// 379.996 us; speedup vs baseline: 5.5642x; 1.0956x over previous
//
#include <hip/hip_runtime.h>

#define IN_C   128
#define HC     128   // HEADS*OUT_C
#define HEADS  4
#define OUT_C  32
#define NEG    0.2f
#define BM     64    // rows per block in GEMM

// bf16 helpers: xh stored packed, 2 channels per uint (ch 2j = low 16 bits).
__device__ __forceinline__ uint bf16_rne(float f) {
    uint u = __float_as_uint(f);
    return (u + 0x7FFFu + ((u >> 16) & 1u)) >> 16;
}
__device__ __forceinline__ uint pack_bf2(float even, float odd) {
    return bf16_rne(even) | (bf16_rne(odd) << 16);
}
__device__ __forceinline__ float bf_lo(uint u) { return __uint_as_float(u << 16); }
__device__ __forceinline__ float bf_hi(uint u) { return __uint_as_float(u & 0xFFFF0000u); }

// ---------------------------------------------------------------------------
// Pass A: xh = x @ W (output packed bf16), plus per-node logits from the f32
// accumulators. Block = 256 threads, 64 rows; thread owns 4 rows x 8 cols.
// ---------------------------------------------------------------------------
__global__ __launch_bounds__(256) void gemm_logits_kernel(
    const float* __restrict__ x, const float* __restrict__ W,
    const float* __restrict__ att_src, const float* __restrict__ att_dst,
    uint* __restrict__ xhb, float* __restrict__ asrc, float* __restrict__ adst,
    int n)
{
    __shared__ float Wl[IN_C * HC];   // 64 KiB
    const int tid = threadIdx.x;
#pragma unroll
    for (int i = 0; i < 16; ++i) {
        const int idx = (i * 256 + tid) * 4;
        *(float4*)&Wl[idx] = *(const float4*)&W[idx];
    }

    const int tx   = tid & 15;
    const int ty   = tid >> 4;
    const int c0   = tx * 4;
    const int row0 = blockIdx.x * BM + ty * 4;

    __syncthreads();

    float acc[4][8];
#pragma unroll
    for (int r = 0; r < 4; ++r)
#pragma unroll
        for (int j = 0; j < 8; ++j) acc[r][j] = 0.f;

    float4 xq[4];
#pragma unroll
    for (int r = 0; r < 4; ++r)
        xq[r] = (row0 + r < n) ? *(const float4*)&x[(size_t)(row0 + r) * IN_C]
                               : make_float4(0.f, 0.f, 0.f, 0.f);

    for (int kc = 0; kc < 32; ++kc) {
        const int k = kc * 4;
        float4 xn[4];
#pragma unroll
        for (int r = 0; r < 4; ++r)
            xn[r] = (kc < 31 && row0 + r < n)
                  ? *(const float4*)&x[(size_t)(row0 + r) * IN_C + k + 4]
                  : make_float4(0.f, 0.f, 0.f, 0.f);
#pragma unroll
        for (int kk = 0; kk < 4; ++kk) {
            const float4 w0 = *(const float4*)&Wl[(k + kk) * HC + c0];
            const float4 w1 = *(const float4*)&Wl[(k + kk) * HC + c0 + 64];
#pragma unroll
            for (int r = 0; r < 4; ++r) {
                const float xv = ((const float*)&xq[r])[kk];
                acc[r][0] = fmaf(xv, w0.x, acc[r][0]);
                acc[r][1] = fmaf(xv, w0.y, acc[r][1]);
                acc[r][2] = fmaf(xv, w0.z, acc[r][2]);
                acc[r][3] = fmaf(xv, w0.w, acc[r][3]);
                acc[r][4] = fmaf(xv, w1.x, acc[r][4]);
                acc[r][5] = fmaf(xv, w1.y, acc[r][5]);
                acc[r][6] = fmaf(xv, w1.z, acc[r][6]);
                acc[r][7] = fmaf(xv, w1.w, acc[r][7]);
            }
        }
#pragma unroll
        for (int r = 0; r < 4; ++r) xq[r] = xn[r];
    }

    // store xh (packed bf16): uint index = row*64 + c/2
#pragma unroll
    for (int r = 0; r < 4; ++r) {
        const int row = row0 + r;
        if (row < n) {
            *(uint2*)&xhb[row * 64 + (c0 >> 1)] =
                make_uint2(pack_bf2(acc[r][0], acc[r][1]),
                           pack_bf2(acc[r][2], acc[r][3]));
            *(uint2*)&xhb[row * 64 + 32 + (c0 >> 1)] =
                make_uint2(pack_bf2(acc[r][4], acc[r][5]),
                           pack_bf2(acc[r][6], acc[r][7]));
        }
    }

    // logits from f32 accumulators
    const float4 as0 = *(const float4*)&att_src[c0];
    const float4 as1 = *(const float4*)&att_src[c0 + 64];
    const float4 ad0 = *(const float4*)&att_dst[c0];
    const float4 ad1 = *(const float4*)&att_dst[c0 + 64];
#pragma unroll
    for (int r = 0; r < 4; ++r) {
        float p0 = acc[r][0]*as0.x + acc[r][1]*as0.y + acc[r][2]*as0.z + acc[r][3]*as0.w;
        float p1 = acc[r][4]*as1.x + acc[r][5]*as1.y + acc[r][6]*as1.z + acc[r][7]*as1.w;
        float q0 = acc[r][0]*ad0.x + acc[r][1]*ad0.y + acc[r][2]*ad0.z + acc[r][3]*ad0.w;
        float q1 = acc[r][4]*ad1.x + acc[r][5]*ad1.y + acc[r][6]*ad1.z + acc[r][7]*ad1.w;
#pragma unroll
        for (int m = 1; m < 8; m <<= 1) {
            p0 += __shfl_xor(p0, m);
            p1 += __shfl_xor(p1, m);
            q0 += __shfl_xor(q0, m);
            q1 += __shfl_xor(q1, m);
        }
        const int row = row0 + r;
        if ((tx & 7) == 0 && row < n) {
            const int h = tx >> 3;
            asrc[row * 4 + h]     = p0;
            asrc[row * 4 + 2 + h] = p1;
            adst[row * 4 + h]     = q0;
            adst[row * 4 + 2 + h] = q1;
        }
    }
}

// ---------------------------------------------------------------------------
// CSR build: histogram of dst degrees
// ---------------------------------------------------------------------------
__global__ __launch_bounds__(256) void hist_kernel(
    const int* __restrict__ dst, int* __restrict__ deg, int E)
{
    const int t = blockIdx.x * 256 + threadIdx.x;
    if (t >= E) return;
    atomicAdd(&deg[dst[t]], 1);
}

// ---------------------------------------------------------------------------
// Exclusive scan over deg[n] -> cursor[n]
// ---------------------------------------------------------------------------
__global__ __launch_bounds__(256) void scan1_kernel(
    const int* __restrict__ deg, int* __restrict__ cursor,
    int* __restrict__ bsum, int n)
{
    __shared__ int sd[256];
    const int t   = threadIdx.x;
    const int idx = blockIdx.x * 1024 + t * 4;

    int4 v = make_int4(0, 0, 0, 0);
    if (idx + 3 < n) {
        v = *(const int4*)&deg[idx];
    } else {
        if (idx     < n) v.x = deg[idx];
        if (idx + 1 < n) v.y = deg[idx + 1];
        if (idx + 2 < n) v.z = deg[idx + 2];
        if (idx + 3 < n) v.w = deg[idx + 3];
    }
    const int s0 = v.x, s1 = s0 + v.y, s2 = s1 + v.z, s3 = s2 + v.w;
    sd[t] = s3;
    __syncthreads();
#pragma unroll
    for (int off = 1; off < 256; off <<= 1) {
        const int val = (t >= off) ? sd[t - off] : 0;
        __syncthreads();
        sd[t] += val;
        __syncthreads();
    }
    const int texcl = (t > 0) ? sd[t - 1] : 0;
    if (t == 255) bsum[blockIdx.x] = sd[255];

    int4 o;
    o.x = texcl; o.y = texcl + s0; o.z = texcl + s1; o.w = texcl + s2;
    if (idx + 3 < n) {
        *(int4*)&cursor[idx] = o;
    } else {
        if (idx     < n) cursor[idx]     = o.x;
        if (idx + 1 < n) cursor[idx + 1] = o.y;
        if (idx + 2 < n) cursor[idx + 2] = o.z;
        if (idx + 3 < n) cursor[idx + 3] = o.w;
    }
}

__global__ __launch_bounds__(256) void scan2_kernel(int* __restrict__ bsum, int B)
{
    __shared__ int sd[256];
    const int t = threadIdx.x;
    sd[t] = (t < B) ? bsum[t] : 0;
    __syncthreads();
#pragma unroll
    for (int off = 1; off < 256; off <<= 1) {
        const int val = (t >= off) ? sd[t - off] : 0;
        __syncthreads();
        sd[t] += val;
        __syncthreads();
    }
    if (t < B) bsum[t] = (t > 0) ? sd[t - 1] : 0;
}

__global__ __launch_bounds__(256) void scan3_kernel(
    int* __restrict__ cursor, const int* __restrict__ bsum, int n)
{
    const int idx = (blockIdx.x * 256 + threadIdx.x) * 4;
    if (idx >= n) return;
    const int add = bsum[idx >> 10];
    if (add == 0) return;
    if (idx + 3 < n) {
        int4 v = *(int4*)&cursor[idx];
        v.x += add; v.y += add; v.z += add; v.w += add;
        *(int4*)&cursor[idx] = v;
    } else {
        if (idx     < n) cursor[idx]     += add;
        if (idx + 1 < n) cursor[idx + 1] += add;
        if (idx + 2 < n) cursor[idx + 2] += add;
        if (idx + 3 < n) cursor[idx + 3] += add;
    }
}

// ---------------------------------------------------------------------------
// Scatter edges into CSR slots. After this, cursor[i] == end offset of node i.
// ---------------------------------------------------------------------------
__global__ __launch_bounds__(256) void scatter_kernel(
    const int* __restrict__ src, const int* __restrict__ dst,
    int* __restrict__ cursor, int* __restrict__ csr_src, int E)
{
    const int t = blockIdx.x * 256 + threadIdx.x;
    if (t >= E) return;
    const int slot = atomicAdd(&cursor[dst[t]], 1);
    csr_src[slot] = src[t];
}

// ---------------------------------------------------------------------------
// Fused aggregate: one wave per dst node. Lean inner loop:
//  - edge index readfirstlane'd -> scalar base addressing for gathers
//  - xh gathered as packed bf16 (4 B/lane, 256 B/wave per edge)
//  - 2-edge unroll for load-level parallelism; TLP hides the rest
// ---------------------------------------------------------------------------
__global__ __launch_bounds__(256) void aggregate_csr_kernel(
    const int* __restrict__ csr_src, const int* __restrict__ cursor,
    const int* __restrict__ deg,
    const float* __restrict__ asrc, const float* __restrict__ adst,
    const uint* __restrict__ xhb, const float* __restrict__ bias,
    float* __restrict__ out, int n)
{
    const int node = blockIdx.x * 4 + (threadIdx.x >> 6);
    if (node >= n) return;
    const int lane = threadIdx.x & 63;
    const int h    = lane >> 4;

    const int end = cursor[node];          // post-scatter == end offset
    const int beg = end - deg[node];

    const float adh = adst[node * 4 + h];

    // self-loop contribution
    {
        const float z = asrc[node * 4 + h] + adh;
        const float w = __expf(fmaxf(z, NEG * z));
        const uint  xs = xhb[node * 64 + lane];
        float acc0 = w * bf_lo(xs);
        float acc1 = w * bf_hi(xs);
        float ssum = w;

        int e = beg;
        for (; e + 1 < end; e += 2) {
            const int sA = __builtin_amdgcn_readfirstlane(csr_src[e]);
            const int sB = __builtin_amdgcn_readfirstlane(csr_src[e + 1]);
            const float aA = asrc[sA * 4 + h];
            const float aB = asrc[sB * 4 + h];
            const uint  xA = xhb[sA * 64 + lane];
            const uint  xB = xhb[sB * 64 + lane];
            const float zA = aA + adh;
            const float zB = aB + adh;
            const float wA = __expf(fmaxf(zA, NEG * zA));
            const float wB = __expf(fmaxf(zB, NEG * zB));
            acc0 = fmaf(wA, bf_lo(xA), acc0);
            acc1 = fmaf(wA, bf_hi(xA), acc1);
            acc0 = fmaf(wB, bf_lo(xB), acc0);
            acc1 = fmaf(wB, bf_hi(xB), acc1);
            ssum += wA + wB;
        }
        if (e < end) {
            const int sA = __builtin_amdgcn_readfirstlane(csr_src[e]);
            const float aA = asrc[sA * 4 + h];
            const uint  xA = xhb[sA * 64 + lane];
            const float zA = aA + adh;
            const float wA = __expf(fmaxf(zA, NEG * zA));
            acc0 = fmaf(wA, bf_lo(xA), acc0);
            acc1 = fmaf(wA, bf_hi(xA), acc1);
            ssum += wA;
        }

        const float inv = 1.f / ssum;
        const float2 b2 = *(const float2*)&bias[2 * lane];
        float r0 = acc0 * inv + b2.x;
        float r1 = acc1 * inv + b2.y;
        *(float2*)&out[node * 128 + 2 * lane] =
            make_float2(r0 > 0.f ? r0 : 0.f, r1 > 0.f ? r1 : 0.f);
    }
}

// ---------------------------------------------------------------------------
extern "C" void kernel_launch(void* const* d_in, const int* in_sizes, int n_in,
                              void* d_out, int out_size, void* d_ws, size_t ws_size,
                              hipStream_t stream)
{
    const float* x       = (const float*)d_in[0];
    const int*   ei      = (const int*)d_in[1];   // [2,E] flat: src then dst
    const float* W       = (const float*)d_in[2];
    const float* att_src = (const float*)d_in[3];
    const float* att_dst = (const float*)d_in[4];
    const float* bias    = (const float*)d_in[5];

    const int n = in_sizes[0] / IN_C;
    const int E = in_sizes[1] / 2;
    const int* src = ei;
    const int* dst = ei + E;

    float* out  = (float*)d_out;

    // workspace layout
    uint*  xhb     = (uint*)d_ws;                         // n*64 uints (25.6MB)
    float* asrc    = (float*)(xhb + (size_t)n * 64);      // n*4
    float* adst    = asrc + (size_t)n * HEADS;            // n*4
    int*   deg     = (int*)(adst + (size_t)n * HEADS);    // n
    int*   cursor  = deg + n;                             // n
    int*   bsum    = cursor + n;                          // 256
    int*   csr_src = bsum + 256;                          // E

    hipMemsetAsync(deg, 0, (size_t)n * sizeof(int), stream);

    gemm_logits_kernel<<<(n + BM - 1) / BM, 256, 0, stream>>>(
        x, W, att_src, att_dst, xhb, asrc, adst, n);

    const int B = (n + 1023) / 1024;   // n<=262144 -> B<=256 (scan2 single block)
    hist_kernel<<<(E + 255) / 256, 256, 0, stream>>>(dst, deg, E);
    scan1_kernel<<<B, 256, 0, stream>>>(deg, cursor, bsum, n);
    scan2_kernel<<<1, 256, 0, stream>>>(bsum, B);
    scan3_kernel<<<B, 256, 0, stream>>>(cursor, bsum, n);
    scatter_kernel<<<(E + 255) / 256, 256, 0, stream>>>(src, dst, cursor,
                                                        csr_src, E);
    aggregate_csr_kernel<<<(n + 3) / 4, 256, 0, stream>>>(csr_src, cursor, deg,
                                                          asrc, adst, xhb, bias,
                                                          out, n);
}

// Round 5
// 243.456 us; speedup vs baseline: 8.6849x; 1.5608x over previous
//
#include <hip/hip_runtime.h>

#define IN_C   128
#define HC     128   // HEADS*OUT_C
#define HEADS  4
#define NEG    0.2f
#define BM     64    // rows per block in GEMM

#define BSH    8     // bucket = dst >> 8  (256 nodes per bucket)
#define KMAX   512   // max buckets (n <= 131072)
#define EPB    4096  // edges per partition block
#define P2CAP  8192  // LDS sort capacity per bucket (mean 4096, sigma 64)

// bf16 helpers: xh stored packed, 2 channels per uint (ch 2j = low 16 bits).
__device__ __forceinline__ uint bf16_rne(float f) {
    uint u = __float_as_uint(f);
    return (u + 0x7FFFu + ((u >> 16) & 1u)) >> 16;
}
__device__ __forceinline__ uint pack_bf2(float even, float odd) {
    return bf16_rne(even) | (bf16_rne(odd) << 16);
}
__device__ __forceinline__ float bf_lo(uint u) { return __uint_as_float(u << 16); }
__device__ __forceinline__ float bf_hi(uint u) { return __uint_as_float(u & 0xFFFF0000u); }

// ---------------------------------------------------------------------------
// Pass A: xh = x @ W (output packed bf16), plus per-node logits from the f32
// accumulators. Block = 256 threads, 64 rows; thread owns 4 rows x 8 cols.
// ---------------------------------------------------------------------------
__global__ __launch_bounds__(256) void gemm_logits_kernel(
    const float* __restrict__ x, const float* __restrict__ W,
    const float* __restrict__ att_src, const float* __restrict__ att_dst,
    uint* __restrict__ xhb, float* __restrict__ asrc, float* __restrict__ adst,
    int n)
{
    __shared__ float Wl[IN_C * HC];   // 64 KiB
    const int tid = threadIdx.x;
#pragma unroll
    for (int i = 0; i < 16; ++i) {
        const int idx = (i * 256 + tid) * 4;
        *(float4*)&Wl[idx] = *(const float4*)&W[idx];
    }

    const int tx   = tid & 15;
    const int ty   = tid >> 4;
    const int c0   = tx * 4;
    const int row0 = blockIdx.x * BM + ty * 4;

    __syncthreads();

    float acc[4][8];
#pragma unroll
    for (int r = 0; r < 4; ++r)
#pragma unroll
        for (int j = 0; j < 8; ++j) acc[r][j] = 0.f;

    float4 xq[4];
#pragma unroll
    for (int r = 0; r < 4; ++r)
        xq[r] = (row0 + r < n) ? *(const float4*)&x[(size_t)(row0 + r) * IN_C]
                               : make_float4(0.f, 0.f, 0.f, 0.f);

    for (int kc = 0; kc < 32; ++kc) {
        const int k = kc * 4;
        float4 xn[4];
#pragma unroll
        for (int r = 0; r < 4; ++r)
            xn[r] = (kc < 31 && row0 + r < n)
                  ? *(const float4*)&x[(size_t)(row0 + r) * IN_C + k + 4]
                  : make_float4(0.f, 0.f, 0.f, 0.f);
#pragma unroll
        for (int kk = 0; kk < 4; ++kk) {
            const float4 w0 = *(const float4*)&Wl[(k + kk) * HC + c0];
            const float4 w1 = *(const float4*)&Wl[(k + kk) * HC + c0 + 64];
#pragma unroll
            for (int r = 0; r < 4; ++r) {
                const float xv = ((const float*)&xq[r])[kk];
                acc[r][0] = fmaf(xv, w0.x, acc[r][0]);
                acc[r][1] = fmaf(xv, w0.y, acc[r][1]);
                acc[r][2] = fmaf(xv, w0.z, acc[r][2]);
                acc[r][3] = fmaf(xv, w0.w, acc[r][3]);
                acc[r][4] = fmaf(xv, w1.x, acc[r][4]);
                acc[r][5] = fmaf(xv, w1.y, acc[r][5]);
                acc[r][6] = fmaf(xv, w1.z, acc[r][6]);
                acc[r][7] = fmaf(xv, w1.w, acc[r][7]);
            }
        }
#pragma unroll
        for (int r = 0; r < 4; ++r) xq[r] = xn[r];
    }

    // store xh (packed bf16): uint index = row*64 + c/2
#pragma unroll
    for (int r = 0; r < 4; ++r) {
        const int row = row0 + r;
        if (row < n) {
            *(uint2*)&xhb[row * 64 + (c0 >> 1)] =
                make_uint2(pack_bf2(acc[r][0], acc[r][1]),
                           pack_bf2(acc[r][2], acc[r][3]));
            *(uint2*)&xhb[row * 64 + 32 + (c0 >> 1)] =
                make_uint2(pack_bf2(acc[r][4], acc[r][5]),
                           pack_bf2(acc[r][6], acc[r][7]));
        }
    }

    // logits from f32 accumulators
    const float4 as0 = *(const float4*)&att_src[c0];
    const float4 as1 = *(const float4*)&att_src[c0 + 64];
    const float4 ad0 = *(const float4*)&att_dst[c0];
    const float4 ad1 = *(const float4*)&att_dst[c0 + 64];
#pragma unroll
    for (int r = 0; r < 4; ++r) {
        float p0 = acc[r][0]*as0.x + acc[r][1]*as0.y + acc[r][2]*as0.z + acc[r][3]*as0.w;
        float p1 = acc[r][4]*as1.x + acc[r][5]*as1.y + acc[r][6]*as1.z + acc[r][7]*as1.w;
        float q0 = acc[r][0]*ad0.x + acc[r][1]*ad0.y + acc[r][2]*ad0.z + acc[r][3]*ad0.w;
        float q1 = acc[r][4]*ad1.x + acc[r][5]*ad1.y + acc[r][6]*ad1.z + acc[r][7]*ad1.w;
#pragma unroll
        for (int m = 1; m < 8; m <<= 1) {
            p0 += __shfl_xor(p0, m);
            p1 += __shfl_xor(p1, m);
            q0 += __shfl_xor(q0, m);
            q1 += __shfl_xor(q1, m);
        }
        const int row = row0 + r;
        if ((tx & 7) == 0 && row < n) {
            const int h = tx >> 3;
            asrc[row * 4 + h]     = p0;
            asrc[row * 4 + 2 + h] = p1;
            adst[row * 4 + h]     = q0;
            adst[row * 4 + 2 + h] = q1;
        }
    }
}

// ---------------------------------------------------------------------------
// P0: bucket counts via per-block LDS histogram (bucket = dst>>8).
// ---------------------------------------------------------------------------
__global__ __launch_bounds__(256) void p0_count_kernel(
    const int* __restrict__ dst, int* __restrict__ bucket_count, int E)
{
    __shared__ int h[KMAX];
    const int t = threadIdx.x;
    h[t] = 0; h[t + 256] = 0;
    __syncthreads();
    const int base = blockIdx.x * EPB;
#pragma unroll
    for (int i = 0; i < EPB / 256; ++i) {
        const int e = base + i * 256 + t;
        if (e < E) atomicAdd(&h[((uint)dst[e]) >> BSH], 1);
    }
    __syncthreads();
    if (h[t])       atomicAdd(&bucket_count[t],       h[t]);
    if (h[t + 256]) atomicAdd(&bucket_count[t + 256], h[t + 256]);
}

// ---------------------------------------------------------------------------
// P0scan: single-WG exclusive scan of 512 bucket counts.
// ---------------------------------------------------------------------------
__global__ __launch_bounds__(256) void p0_scan_kernel(
    const int* __restrict__ bucket_count, int* __restrict__ bucket_start,
    int* __restrict__ bucket_cursor)
{
    __shared__ int sd[256];
    const int t = threadIdx.x;
    const int a = bucket_count[2 * t], b = bucket_count[2 * t + 1];
    sd[t] = a + b;
    __syncthreads();
#pragma unroll
    for (int off = 1; off < 256; off <<= 1) {
        const int v = (t >= off) ? sd[t - off] : 0;
        __syncthreads();
        sd[t] += v;
        __syncthreads();
    }
    const int base = t ? sd[t - 1] : 0;
    bucket_start[2 * t]      = base;     bucket_cursor[2 * t]      = base;
    bucket_start[2 * t + 1]  = base + a; bucket_cursor[2 * t + 1]  = base + a;
}

// ---------------------------------------------------------------------------
// P1: partition edges into bucket-contiguous staging (src,dst pairs).
// Per-block LDS counting sort by bucket -> bucket-contiguous global writes.
// ---------------------------------------------------------------------------
__global__ __launch_bounds__(256) void p1_partition_kernel(
    const int* __restrict__ src, const int* __restrict__ dst,
    int* __restrict__ bucket_cursor, uint2* __restrict__ staged, int E)
{
    __shared__ int  hist[KMAX];
    __shared__ int  lbase[KMAX];
    __shared__ int  gbase[KMAX];
    __shared__ int  lcur[KMAX];
    __shared__ int  sd[256];
    __shared__ uint2 stage[EPB];   // 32 KiB
    const int t = threadIdx.x;
    hist[t] = 0; hist[t + 256] = 0;
    __syncthreads();

    const int base = blockIdx.x * EPB;
    uint sv[EPB / 256], dv[EPB / 256];
#pragma unroll
    for (int i = 0; i < EPB / 256; ++i) {
        const int e = base + i * 256 + t;
        if (e < E) {
            sv[i] = (uint)src[e];
            dv[i] = (uint)dst[e];
            atomicAdd(&hist[dv[i] >> BSH], 1);
        } else {
            dv[i] = 0xFFFFFFFFu;
        }
    }
    __syncthreads();

    // exclusive scan of hist[512]
    const int h0 = hist[2 * t], h1 = hist[2 * t + 1];
    sd[t] = h0 + h1;
    __syncthreads();
#pragma unroll
    for (int off = 1; off < 256; off <<= 1) {
        const int v = (t >= off) ? sd[t - off] : 0;
        __syncthreads();
        sd[t] += v;
        __syncthreads();
    }
    const int b2 = t ? sd[t - 1] : 0;
    lbase[2 * t]     = b2;      lcur[2 * t]     = b2;
    lbase[2 * t + 1] = b2 + h0; lcur[2 * t + 1] = b2 + h0;
    gbase[2 * t]     = h0 ? atomicAdd(&bucket_cursor[2 * t],     h0) : 0;
    gbase[2 * t + 1] = h1 ? atomicAdd(&bucket_cursor[2 * t + 1], h1) : 0;
    __syncthreads();

    // place edges into LDS staging, grouped by bucket
#pragma unroll
    for (int i = 0; i < EPB / 256; ++i) {
        if (dv[i] != 0xFFFFFFFFu) {
            const int slot = atomicAdd(&lcur[dv[i] >> BSH], 1);
            stage[slot] = make_uint2(sv[i], dv[i]);
        }
    }
    __syncthreads();

    // bucket-contiguous write-out
    const int total = sd[255];
    for (int j = t; j < total; j += 256) {
        const uint2 ev = stage[j];
        const int b = ev.y >> BSH;
        staged[gbase[b] + (j - lbase[b])] = ev;
    }
}

// ---------------------------------------------------------------------------
// P2: one WG per bucket. LDS counting sort by node -> coalesced csr_src write,
// plus node_beg / deg emitted directly (replaces global hist+scan+scatter).
// ---------------------------------------------------------------------------
__global__ __launch_bounds__(256) void p2_csr_kernel(
    const uint2* __restrict__ staged, const int* __restrict__ bucket_start,
    const int* __restrict__ bucket_count,
    int* __restrict__ csr_src, int* __restrict__ node_beg,
    int* __restrict__ deg_out, int n)
{
    __shared__ int deg[256];
    __shared__ int cur[256];
    __shared__ int sd[256];
    __shared__ int sorted[P2CAP];   // 32 KiB
    const int b  = blockIdx.x;
    const int t  = threadIdx.x;
    const int eb = bucket_start[b];
    const int cnt = min(bucket_count[b], P2CAP);
    const int v0 = b << BSH;

    deg[t] = 0;
    __syncthreads();
    for (int i = t; i < cnt; i += 256)
        atomicAdd(&deg[staged[eb + i].y & 255], 1);
    __syncthreads();

    const int d = deg[t];
    sd[t] = d;
    __syncthreads();
#pragma unroll
    for (int off = 1; off < 256; off <<= 1) {
        const int v = (t >= off) ? sd[t - off] : 0;
        __syncthreads();
        sd[t] += v;
        __syncthreads();
    }
    const int excl = t ? sd[t - 1] : 0;
    cur[t] = excl;
    if (v0 + t < n) {
        node_beg[v0 + t] = eb + excl;
        deg_out[v0 + t]  = d;
    }
    __syncthreads();

    for (int i = t; i < cnt; i += 256) {
        const uint2 ev = staged[eb + i];
        const int slot = atomicAdd(&cur[ev.y & 255], 1);
        sorted[slot] = (int)ev.x;
    }
    __syncthreads();

    for (int i = t; i < cnt; i += 256)
        csr_src[eb + i] = sorted[i];
}

// ---------------------------------------------------------------------------
// Fused aggregate: one wave per dst node (unchanged from round 4 except
// node_beg/deg interface).
// ---------------------------------------------------------------------------
__global__ __launch_bounds__(256) void aggregate_csr_kernel(
    const int* __restrict__ csr_src, const int* __restrict__ node_beg,
    const int* __restrict__ deg,
    const float* __restrict__ asrc, const float* __restrict__ adst,
    const uint* __restrict__ xhb, const float* __restrict__ bias,
    float* __restrict__ out, int n)
{
    const int node = blockIdx.x * 4 + (threadIdx.x >> 6);
    if (node >= n) return;
    const int lane = threadIdx.x & 63;
    const int h    = lane >> 4;

    const int beg = node_beg[node];
    const int end = beg + deg[node];

    const float adh = adst[node * 4 + h];

    const float z = asrc[node * 4 + h] + adh;
    const float w = __expf(fmaxf(z, NEG * z));
    const uint  xs = xhb[node * 64 + lane];
    float acc0 = w * bf_lo(xs);
    float acc1 = w * bf_hi(xs);
    float ssum = w;

    int e = beg;
    for (; e + 1 < end; e += 2) {
        const int sA = __builtin_amdgcn_readfirstlane(csr_src[e]);
        const int sB = __builtin_amdgcn_readfirstlane(csr_src[e + 1]);
        const float aA = asrc[sA * 4 + h];
        const float aB = asrc[sB * 4 + h];
        const uint  xA = xhb[sA * 64 + lane];
        const uint  xB = xhb[sB * 64 + lane];
        const float zA = aA + adh;
        const float zB = aB + adh;
        const float wA = __expf(fmaxf(zA, NEG * zA));
        const float wB = __expf(fmaxf(zB, NEG * zB));
        acc0 = fmaf(wA, bf_lo(xA), acc0);
        acc1 = fmaf(wA, bf_hi(xA), acc1);
        acc0 = fmaf(wB, bf_lo(xB), acc0);
        acc1 = fmaf(wB, bf_hi(xB), acc1);
        ssum += wA + wB;
    }
    if (e < end) {
        const int sA = __builtin_amdgcn_readfirstlane(csr_src[e]);
        const float aA = asrc[sA * 4 + h];
        const uint  xA = xhb[sA * 64 + lane];
        const float zA = aA + adh;
        const float wA = __expf(fmaxf(zA, NEG * zA));
        acc0 = fmaf(wA, bf_lo(xA), acc0);
        acc1 = fmaf(wA, bf_hi(xA), acc1);
        ssum += wA;
    }

    const float inv = 1.f / ssum;
    const float2 b2 = *(const float2*)&bias[2 * lane];
    float r0 = acc0 * inv + b2.x;
    float r1 = acc1 * inv + b2.y;
    *(float2*)&out[node * 128 + 2 * lane] =
        make_float2(r0 > 0.f ? r0 : 0.f, r1 > 0.f ? r1 : 0.f);
}

// ---------------------------------------------------------------------------
extern "C" void kernel_launch(void* const* d_in, const int* in_sizes, int n_in,
                              void* d_out, int out_size, void* d_ws, size_t ws_size,
                              hipStream_t stream)
{
    const float* x       = (const float*)d_in[0];
    const int*   ei      = (const int*)d_in[1];   // [2,E] flat: src then dst
    const float* W       = (const float*)d_in[2];
    const float* att_src = (const float*)d_in[3];
    const float* att_dst = (const float*)d_in[4];
    const float* bias    = (const float*)d_in[5];

    const int n = in_sizes[0] / IN_C;
    const int E = in_sizes[1] / 2;
    const int* src = ei;
    const int* dst = ei + E;

    float* out = (float*)d_out;

    // workspace layout (all 4-byte units; staged offset is 8B-aligned for n even)
    uint*  xhb       = (uint*)d_ws;                        // n*64
    float* asrc      = (float*)(xhb + (size_t)n * 64);     // n*4
    float* adst      = asrc + (size_t)n * HEADS;           // n*4
    int*   node_beg  = (int*)(adst + (size_t)n * HEADS);   // n
    int*   deg       = node_beg + n;                       // n
    int*   bcount    = deg + n;                            // 512
    int*   bstart    = bcount + 512;                       // 512
    int*   bcursor   = bstart + 512;                       // 512
    uint2* staged    = (uint2*)(bcursor + 512);            // E pairs (8B each)
    int*   csr_src   = (int*)(staged + (size_t)E);         // E

    const int K   = (n + 255) >> BSH;            // buckets
    const int NB  = (E + EPB - 1) / EPB;         // partition blocks

    hipMemsetAsync(bcount, 0, 512 * sizeof(int), stream);

    gemm_logits_kernel<<<(n + BM - 1) / BM, 256, 0, stream>>>(
        x, W, att_src, att_dst, xhb, asrc, adst, n);

    p0_count_kernel<<<NB, 256, 0, stream>>>(dst, bcount, E);
    p0_scan_kernel<<<1, 256, 0, stream>>>(bcount, bstart, bcursor);
    p1_partition_kernel<<<NB, 256, 0, stream>>>(src, dst, bcursor, staged, E);
    p2_csr_kernel<<<K, 256, 0, stream>>>(staged, bstart, bcount,
                                         csr_src, node_beg, deg, n);
    aggregate_csr_kernel<<<(n + 3) / 4, 256, 0, stream>>>(csr_src, node_beg, deg,
                                                          asrc, adst, xhb, bias,
                                                          out, n);
}

// Round 6
// 216.831 us; speedup vs baseline: 9.7513x; 1.1228x over previous
//
#include <hip/hip_runtime.h>

#define IN_C   128
#define HC     128   // HEADS*OUT_C
#define HEADS  4
#define NEG    0.2f
#define BM     64    // rows per block in GEMM

#define BSH    8     // bucket = dst >> 8  (256 nodes per bucket)
#define KMAX   512   // max buckets (n <= 131072)
#define EPB    4096  // edges per partition block
#define P2CAP  8192  // LDS sort capacity per bucket (mean 4096, sigma 64)

// bf16 helpers: xh stored packed, 2 channels per uint (ch 2j = low 16 bits).
__device__ __forceinline__ uint bf16_rne(float f) {
    uint u = __float_as_uint(f);
    return (u + 0x7FFFu + ((u >> 16) & 1u)) >> 16;
}
__device__ __forceinline__ uint pack_bf2(float even, float odd) {
    return bf16_rne(even) | (bf16_rne(odd) << 16);
}
__device__ __forceinline__ float bf_lo(uint u) { return __uint_as_float(u << 16); }
__device__ __forceinline__ float bf_hi(uint u) { return __uint_as_float(u & 0xFFFF0000u); }

// ---------------------------------------------------------------------------
// Pass A: xh = x @ W (output packed bf16), plus per-node logits from the f32
// accumulators. Block = 256 threads, 64 rows; thread owns 4 rows x 8 cols.
// ---------------------------------------------------------------------------
__global__ __launch_bounds__(256) void gemm_logits_kernel(
    const float* __restrict__ x, const float* __restrict__ W,
    const float* __restrict__ att_src, const float* __restrict__ att_dst,
    uint* __restrict__ xhb, float* __restrict__ asrc, float* __restrict__ adst,
    int n)
{
    __shared__ float Wl[IN_C * HC];   // 64 KiB
    const int tid = threadIdx.x;
#pragma unroll
    for (int i = 0; i < 16; ++i) {
        const int idx = (i * 256 + tid) * 4;
        *(float4*)&Wl[idx] = *(const float4*)&W[idx];
    }

    const int tx   = tid & 15;
    const int ty   = tid >> 4;
    const int c0   = tx * 4;
    const int row0 = blockIdx.x * BM + ty * 4;

    __syncthreads();

    float acc[4][8];
#pragma unroll
    for (int r = 0; r < 4; ++r)
#pragma unroll
        for (int j = 0; j < 8; ++j) acc[r][j] = 0.f;

    float4 xq[4];
#pragma unroll
    for (int r = 0; r < 4; ++r)
        xq[r] = (row0 + r < n) ? *(const float4*)&x[(size_t)(row0 + r) * IN_C]
                               : make_float4(0.f, 0.f, 0.f, 0.f);

    for (int kc = 0; kc < 32; ++kc) {
        const int k = kc * 4;
        float4 xn[4];
#pragma unroll
        for (int r = 0; r < 4; ++r)
            xn[r] = (kc < 31 && row0 + r < n)
                  ? *(const float4*)&x[(size_t)(row0 + r) * IN_C + k + 4]
                  : make_float4(0.f, 0.f, 0.f, 0.f);
#pragma unroll
        for (int kk = 0; kk < 4; ++kk) {
            const float4 w0 = *(const float4*)&Wl[(k + kk) * HC + c0];
            const float4 w1 = *(const float4*)&Wl[(k + kk) * HC + c0 + 64];
#pragma unroll
            for (int r = 0; r < 4; ++r) {
                const float xv = ((const float*)&xq[r])[kk];
                acc[r][0] = fmaf(xv, w0.x, acc[r][0]);
                acc[r][1] = fmaf(xv, w0.y, acc[r][1]);
                acc[r][2] = fmaf(xv, w0.z, acc[r][2]);
                acc[r][3] = fmaf(xv, w0.w, acc[r][3]);
                acc[r][4] = fmaf(xv, w1.x, acc[r][4]);
                acc[r][5] = fmaf(xv, w1.y, acc[r][5]);
                acc[r][6] = fmaf(xv, w1.z, acc[r][6]);
                acc[r][7] = fmaf(xv, w1.w, acc[r][7]);
            }
        }
#pragma unroll
        for (int r = 0; r < 4; ++r) xq[r] = xn[r];
    }

    // store xh (packed bf16): uint index = row*64 + c/2
#pragma unroll
    for (int r = 0; r < 4; ++r) {
        const int row = row0 + r;
        if (row < n) {
            *(uint2*)&xhb[row * 64 + (c0 >> 1)] =
                make_uint2(pack_bf2(acc[r][0], acc[r][1]),
                           pack_bf2(acc[r][2], acc[r][3]));
            *(uint2*)&xhb[row * 64 + 32 + (c0 >> 1)] =
                make_uint2(pack_bf2(acc[r][4], acc[r][5]),
                           pack_bf2(acc[r][6], acc[r][7]));
        }
    }

    // logits from f32 accumulators
    const float4 as0 = *(const float4*)&att_src[c0];
    const float4 as1 = *(const float4*)&att_src[c0 + 64];
    const float4 ad0 = *(const float4*)&att_dst[c0];
    const float4 ad1 = *(const float4*)&att_dst[c0 + 64];
#pragma unroll
    for (int r = 0; r < 4; ++r) {
        float p0 = acc[r][0]*as0.x + acc[r][1]*as0.y + acc[r][2]*as0.z + acc[r][3]*as0.w;
        float p1 = acc[r][4]*as1.x + acc[r][5]*as1.y + acc[r][6]*as1.z + acc[r][7]*as1.w;
        float q0 = acc[r][0]*ad0.x + acc[r][1]*ad0.y + acc[r][2]*ad0.z + acc[r][3]*ad0.w;
        float q1 = acc[r][4]*ad1.x + acc[r][5]*ad1.y + acc[r][6]*ad1.z + acc[r][7]*ad1.w;
#pragma unroll
        for (int m = 1; m < 8; m <<= 1) {
            p0 += __shfl_xor(p0, m);
            p1 += __shfl_xor(p1, m);
            q0 += __shfl_xor(q0, m);
            q1 += __shfl_xor(q1, m);
        }
        const int row = row0 + r;
        if ((tx & 7) == 0 && row < n) {
            const int h = tx >> 3;
            asrc[row * 4 + h]     = p0;
            asrc[row * 4 + 2 + h] = p1;
            adst[row * 4 + h]     = q0;
            adst[row * 4 + 2 + h] = q1;
        }
    }
}

// ---------------------------------------------------------------------------
// P0: bucket counts via per-block LDS histogram (bucket = dst>>8).
// ---------------------------------------------------------------------------
__global__ __launch_bounds__(256) void p0_count_kernel(
    const int* __restrict__ dst, int* __restrict__ bucket_count, int E)
{
    __shared__ int h[KMAX];
    const int t = threadIdx.x;
    h[t] = 0; h[t + 256] = 0;
    __syncthreads();
    const int base = blockIdx.x * EPB;
#pragma unroll
    for (int i = 0; i < EPB / 256; ++i) {
        const int e = base + i * 256 + t;
        if (e < E) atomicAdd(&h[((uint)dst[e]) >> BSH], 1);
    }
    __syncthreads();
    if (h[t])       atomicAdd(&bucket_count[t],       h[t]);
    if (h[t + 256]) atomicAdd(&bucket_count[t + 256], h[t + 256]);
}

// ---------------------------------------------------------------------------
// P0scan: single-WG exclusive scan of 512 bucket counts.
// ---------------------------------------------------------------------------
__global__ __launch_bounds__(256) void p0_scan_kernel(
    const int* __restrict__ bucket_count, int* __restrict__ bucket_start,
    int* __restrict__ bucket_cursor)
{
    __shared__ int sd[256];
    const int t = threadIdx.x;
    const int a = bucket_count[2 * t], b = bucket_count[2 * t + 1];
    sd[t] = a + b;
    __syncthreads();
#pragma unroll
    for (int off = 1; off < 256; off <<= 1) {
        const int v = (t >= off) ? sd[t - off] : 0;
        __syncthreads();
        sd[t] += v;
        __syncthreads();
    }
    const int base = t ? sd[t - 1] : 0;
    bucket_start[2 * t]      = base;     bucket_cursor[2 * t]      = base;
    bucket_start[2 * t + 1]  = base + a; bucket_cursor[2 * t + 1]  = base + a;
}

// ---------------------------------------------------------------------------
// P1: partition edges into bucket-contiguous staging (src,dst pairs).
// Per-block LDS counting sort by bucket -> bucket-contiguous global writes.
// ---------------------------------------------------------------------------
__global__ __launch_bounds__(256) void p1_partition_kernel(
    const int* __restrict__ src, const int* __restrict__ dst,
    int* __restrict__ bucket_cursor, uint2* __restrict__ staged, int E)
{
    __shared__ int  hist[KMAX];
    __shared__ int  lbase[KMAX];
    __shared__ int  gbase[KMAX];
    __shared__ int  lcur[KMAX];
    __shared__ int  sd[256];
    __shared__ uint2 stage[EPB];   // 32 KiB
    const int t = threadIdx.x;
    hist[t] = 0; hist[t + 256] = 0;
    __syncthreads();

    const int base = blockIdx.x * EPB;
    uint sv[EPB / 256], dv[EPB / 256];
#pragma unroll
    for (int i = 0; i < EPB / 256; ++i) {
        const int e = base + i * 256 + t;
        if (e < E) {
            sv[i] = (uint)src[e];
            dv[i] = (uint)dst[e];
            atomicAdd(&hist[dv[i] >> BSH], 1);
        } else {
            dv[i] = 0xFFFFFFFFu;
        }
    }
    __syncthreads();

    // exclusive scan of hist[512]
    const int h0 = hist[2 * t], h1 = hist[2 * t + 1];
    sd[t] = h0 + h1;
    __syncthreads();
#pragma unroll
    for (int off = 1; off < 256; off <<= 1) {
        const int v = (t >= off) ? sd[t - off] : 0;
        __syncthreads();
        sd[t] += v;
        __syncthreads();
    }
    const int b2 = t ? sd[t - 1] : 0;
    lbase[2 * t]     = b2;      lcur[2 * t]     = b2;
    lbase[2 * t + 1] = b2 + h0; lcur[2 * t + 1] = b2 + h0;
    gbase[2 * t]     = h0 ? atomicAdd(&bucket_cursor[2 * t],     h0) : 0;
    gbase[2 * t + 1] = h1 ? atomicAdd(&bucket_cursor[2 * t + 1], h1) : 0;
    __syncthreads();

    // place edges into LDS staging, grouped by bucket
#pragma unroll
    for (int i = 0; i < EPB / 256; ++i) {
        if (dv[i] != 0xFFFFFFFFu) {
            const int slot = atomicAdd(&lcur[dv[i] >> BSH], 1);
            stage[slot] = make_uint2(sv[i], dv[i]);
        }
    }
    __syncthreads();

    // bucket-contiguous write-out
    const int total = sd[255];
    for (int j = t; j < total; j += 256) {
        const uint2 ev = stage[j];
        const int b = ev.y >> BSH;
        staged[gbase[b] + (j - lbase[b])] = ev;
    }
}

// ---------------------------------------------------------------------------
// P2: one WG per bucket. LDS counting sort by node -> coalesced csr_src write,
// plus node_beg / deg emitted directly (replaces global hist+scan+scatter).
// ---------------------------------------------------------------------------
__global__ __launch_bounds__(256) void p2_csr_kernel(
    const uint2* __restrict__ staged, const int* __restrict__ bucket_start,
    const int* __restrict__ bucket_count,
    int* __restrict__ csr_src, int* __restrict__ node_beg,
    int* __restrict__ deg_out, int n)
{
    __shared__ int deg[256];
    __shared__ int cur[256];
    __shared__ int sd[256];
    __shared__ int sorted[P2CAP];   // 32 KiB
    const int b  = blockIdx.x;
    const int t  = threadIdx.x;
    const int eb = bucket_start[b];
    const int cnt = min(bucket_count[b], P2CAP);
    const int v0 = b << BSH;

    deg[t] = 0;
    __syncthreads();
    for (int i = t; i < cnt; i += 256)
        atomicAdd(&deg[staged[eb + i].y & 255], 1);
    __syncthreads();

    const int d = deg[t];
    sd[t] = d;
    __syncthreads();
#pragma unroll
    for (int off = 1; off < 256; off <<= 1) {
        const int v = (t >= off) ? sd[t - off] : 0;
        __syncthreads();
        sd[t] += v;
        __syncthreads();
    }
    const int excl = t ? sd[t - 1] : 0;
    cur[t] = excl;
    if (v0 + t < n) {
        node_beg[v0 + t] = eb + excl;
        deg_out[v0 + t]  = d;
    }
    __syncthreads();

    for (int i = t; i < cnt; i += 256) {
        const uint2 ev = staged[eb + i];
        const int slot = atomicAdd(&cur[ev.y & 255], 1);
        sorted[slot] = (int)ev.x;
    }
    __syncthreads();

    for (int i = t; i < cnt; i += 256)
        csr_src[eb + i] = sorted[i];
}

// ---------------------------------------------------------------------------
// Fused aggregate v3: one wave per dst node, 4 edges per iteration.
//  - subgroup sub=lane>>4 owns edge e+sub; lane l16=lane&15 owns channels
//    [l16*8, l16*8+8) gathered as one uint4 (coalesced 256B per edge row)
//  - exp/logit-gather/loop overhead paid once per 4 edges
//  - all addressing 32-bit uint off SGPR bases
//  - epilogue: shfl_xor(16,32) cross-subgroup reduce, subgroup 0 writes row
// ---------------------------------------------------------------------------
__global__ __launch_bounds__(256) void aggregate_csr_kernel(
    const int* __restrict__ csr_src, const int* __restrict__ node_beg,
    const int* __restrict__ deg,
    const float* __restrict__ asrc, const float* __restrict__ adst,
    const uint* __restrict__ xhb, const float* __restrict__ bias,
    float* __restrict__ out, int n)
{
    const int node = blockIdx.x * 4 + (threadIdx.x >> 6);
    if (node >= n) return;
    const int  lane = threadIdx.x & 63;
    const int  sub  = lane >> 4;       // subgroup: which of 4 edges
    const uint l16  = lane & 15;       // lane within subgroup
    const uint h    = l16 >> 2;        // head 0..3
    const uint coff = l16 * 4u;        // uint offset of this lane's uint4

    const int beg = node_beg[node];
    const int end = beg + deg[node];

    const float adh = adst[(uint)node * 4u + h];

    // self-loop (subgroup 0 only; others contribute 0)
    const float zs = asrc[(uint)node * 4u + h] + adh;
    const float ws = (sub == 0) ? __expf(fmaxf(zs, NEG * zs)) : 0.f;
    const uint4 xs = *(const uint4*)&xhb[(uint)node * 64u + coff];
    float acc[8];
    acc[0] = ws * bf_lo(xs.x); acc[1] = ws * bf_hi(xs.x);
    acc[2] = ws * bf_lo(xs.y); acc[3] = ws * bf_hi(xs.y);
    acc[4] = ws * bf_lo(xs.z); acc[5] = ws * bf_hi(xs.z);
    acc[6] = ws * bf_lo(xs.w); acc[7] = ws * bf_hi(xs.w);
    float ssum = ws;

    for (int e = beg; e < end; e += 4) {
        const int  eg    = e + sub;
        const bool valid = eg < end;
        const uint s     = valid ? (uint)csr_src[eg] : (uint)node;
        const float z    = asrc[s * 4u + h] + adh;
        float w = __expf(fmaxf(z, NEG * z));
        w = valid ? w : 0.f;
        const uint4 xv = *(const uint4*)&xhb[s * 64u + coff];
        acc[0] = fmaf(w, bf_lo(xv.x), acc[0]);
        acc[1] = fmaf(w, bf_hi(xv.x), acc[1]);
        acc[2] = fmaf(w, bf_lo(xv.y), acc[2]);
        acc[3] = fmaf(w, bf_hi(xv.y), acc[3]);
        acc[4] = fmaf(w, bf_lo(xv.z), acc[4]);
        acc[5] = fmaf(w, bf_hi(xv.z), acc[5]);
        acc[6] = fmaf(w, bf_lo(xv.w), acc[6]);
        acc[7] = fmaf(w, bf_hi(xv.w), acc[7]);
        ssum += w;
    }

    // cross-subgroup reduction (4 partial sums at stride 16)
    ssum += __shfl_xor(ssum, 16);
    ssum += __shfl_xor(ssum, 32);
#pragma unroll
    for (int j = 0; j < 8; ++j) {
        acc[j] += __shfl_xor(acc[j], 16);
        acc[j] += __shfl_xor(acc[j], 32);
    }

    if (sub == 0) {
        const float inv = 1.f / ssum;
        const uint  c   = l16 * 8u;
        const float4 b0 = *(const float4*)&bias[c];
        const float4 b1 = *(const float4*)&bias[c + 4];
        float4 o0, o1;
        o0.x = fmaf(acc[0], inv, b0.x); o0.y = fmaf(acc[1], inv, b0.y);
        o0.z = fmaf(acc[2], inv, b0.z); o0.w = fmaf(acc[3], inv, b0.w);
        o1.x = fmaf(acc[4], inv, b1.x); o1.y = fmaf(acc[5], inv, b1.y);
        o1.z = fmaf(acc[6], inv, b1.z); o1.w = fmaf(acc[7], inv, b1.w);
        o0.x = fmaxf(o0.x, 0.f); o0.y = fmaxf(o0.y, 0.f);
        o0.z = fmaxf(o0.z, 0.f); o0.w = fmaxf(o0.w, 0.f);
        o1.x = fmaxf(o1.x, 0.f); o1.y = fmaxf(o1.y, 0.f);
        o1.z = fmaxf(o1.z, 0.f); o1.w = fmaxf(o1.w, 0.f);
        *(float4*)&out[(uint)node * 128u + c]      = o0;
        *(float4*)&out[(uint)node * 128u + c + 4u] = o1;
    }
}

// ---------------------------------------------------------------------------
extern "C" void kernel_launch(void* const* d_in, const int* in_sizes, int n_in,
                              void* d_out, int out_size, void* d_ws, size_t ws_size,
                              hipStream_t stream)
{
    const float* x       = (const float*)d_in[0];
    const int*   ei      = (const int*)d_in[1];   // [2,E] flat: src then dst
    const float* W       = (const float*)d_in[2];
    const float* att_src = (const float*)d_in[3];
    const float* att_dst = (const float*)d_in[4];
    const float* bias    = (const float*)d_in[5];

    const int n = in_sizes[0] / IN_C;
    const int E = in_sizes[1] / 2;
    const int* src = ei;
    const int* dst = ei + E;

    float* out = (float*)d_out;

    // workspace layout (all 4-byte units; staged offset is 8B-aligned for n even)
    uint*  xhb       = (uint*)d_ws;                        // n*64
    float* asrc      = (float*)(xhb + (size_t)n * 64);     // n*4
    float* adst      = asrc + (size_t)n * HEADS;           // n*4
    int*   node_beg  = (int*)(adst + (size_t)n * HEADS);   // n
    int*   deg       = node_beg + n;                       // n
    int*   bcount    = deg + n;                            // 512
    int*   bstart    = bcount + 512;                       // 512
    int*   bcursor   = bstart + 512;                       // 512
    uint2* staged    = (uint2*)(bcursor + 512);            // E pairs (8B each)
    int*   csr_src   = (int*)(staged + (size_t)E);         // E (+4 slack follows)

    const int K   = (n + 255) >> BSH;            // buckets
    const int NB  = (E + EPB - 1) / EPB;         // partition blocks

    hipMemsetAsync(bcount, 0, 512 * sizeof(int), stream);

    gemm_logits_kernel<<<(n + BM - 1) / BM, 256, 0, stream>>>(
        x, W, att_src, att_dst, xhb, asrc, adst, n);

    p0_count_kernel<<<NB, 256, 0, stream>>>(dst, bcount, E);
    p0_scan_kernel<<<1, 256, 0, stream>>>(bcount, bstart, bcursor);
    p1_partition_kernel<<<NB, 256, 0, stream>>>(src, dst, bcursor, staged, E);
    p2_csr_kernel<<<K, 256, 0, stream>>>(staged, bstart, bcount,
                                         csr_src, node_beg, deg, n);
    aggregate_csr_kernel<<<(n + 3) / 4, 256, 0, stream>>>(csr_src, node_beg, deg,
                                                          asrc, adst, xhb, bias,
                                                          out, n);
}

// Round 7
// 212.408 us; speedup vs baseline: 9.9544x; 1.0208x over previous
//
#include <hip/hip_runtime.h>

#define IN_C   128
#define HC     128   // HEADS*OUT_C
#define HEADS  4
#define NEG    0.2f
#define BM     128   // rows per block in GEMM (512 threads)

#define BSH    8     // bucket = dst >> 8  (256 nodes per bucket)
#define KMAX   512   // max buckets (n <= 131072)
#define EPB    4096  // edges per partition block
#define P2CAP  8192  // LDS sort capacity per bucket (mean 4096, sigma 64)

// bf16 helpers: xh stored packed, 2 channels per uint (ch 2j = low 16 bits).
__device__ __forceinline__ uint bf16_rne(float f) {
    uint u = __float_as_uint(f);
    return (u + 0x7FFFu + ((u >> 16) & 1u)) >> 16;
}
__device__ __forceinline__ uint pack_bf2(float even, float odd) {
    return bf16_rne(even) | (bf16_rne(odd) << 16);
}
__device__ __forceinline__ float bf_lo(uint u) { return __uint_as_float(u << 16); }
__device__ __forceinline__ float bf_hi(uint u) { return __uint_as_float(u & 0xFFFF0000u); }

// ---------------------------------------------------------------------------
// Pass A: xh = x @ W (output packed bf16), plus per-node logits from the f32
// accumulators. Block = 512 threads, 128 rows; thread owns 4 rows x 8 cols.
// 64 KiB LDS -> 2 blocks/CU -> 16 waves/CU (vs 8 at 256-thread blocks).
// ---------------------------------------------------------------------------
__global__ __launch_bounds__(512) void gemm_logits_kernel(
    const float* __restrict__ x, const float* __restrict__ W,
    const float* __restrict__ att_src, const float* __restrict__ att_dst,
    uint* __restrict__ xhb, float* __restrict__ asrc, float* __restrict__ adst,
    int n)
{
    __shared__ float Wl[IN_C * HC];   // 64 KiB
    const int tid = threadIdx.x;
#pragma unroll
    for (int i = 0; i < 8; ++i) {
        const int idx = (i * 512 + tid) * 4;
        *(float4*)&Wl[idx] = *(const float4*)&W[idx];
    }

    const int tx   = tid & 15;
    const int ty   = tid >> 4;        // 0..31
    const int c0   = tx * 4;
    const int row0 = blockIdx.x * BM + ty * 4;

    __syncthreads();

    float acc[4][8];
#pragma unroll
    for (int r = 0; r < 4; ++r)
#pragma unroll
        for (int j = 0; j < 8; ++j) acc[r][j] = 0.f;

    float4 xq[4];
#pragma unroll
    for (int r = 0; r < 4; ++r)
        xq[r] = (row0 + r < n) ? *(const float4*)&x[(size_t)(row0 + r) * IN_C]
                               : make_float4(0.f, 0.f, 0.f, 0.f);

    for (int kc = 0; kc < 32; ++kc) {
        const int k = kc * 4;
        float4 xn[4];
#pragma unroll
        for (int r = 0; r < 4; ++r)
            xn[r] = (kc < 31 && row0 + r < n)
                  ? *(const float4*)&x[(size_t)(row0 + r) * IN_C + k + 4]
                  : make_float4(0.f, 0.f, 0.f, 0.f);
#pragma unroll
        for (int kk = 0; kk < 4; ++kk) {
            const float4 w0 = *(const float4*)&Wl[(k + kk) * HC + c0];
            const float4 w1 = *(const float4*)&Wl[(k + kk) * HC + c0 + 64];
#pragma unroll
            for (int r = 0; r < 4; ++r) {
                const float xv = ((const float*)&xq[r])[kk];
                acc[r][0] = fmaf(xv, w0.x, acc[r][0]);
                acc[r][1] = fmaf(xv, w0.y, acc[r][1]);
                acc[r][2] = fmaf(xv, w0.z, acc[r][2]);
                acc[r][3] = fmaf(xv, w0.w, acc[r][3]);
                acc[r][4] = fmaf(xv, w1.x, acc[r][4]);
                acc[r][5] = fmaf(xv, w1.y, acc[r][5]);
                acc[r][6] = fmaf(xv, w1.z, acc[r][6]);
                acc[r][7] = fmaf(xv, w1.w, acc[r][7]);
            }
        }
#pragma unroll
        for (int r = 0; r < 4; ++r) xq[r] = xn[r];
    }

    // store xh (packed bf16): uint index = row*64 + c/2
#pragma unroll
    for (int r = 0; r < 4; ++r) {
        const int row = row0 + r;
        if (row < n) {
            *(uint2*)&xhb[row * 64 + (c0 >> 1)] =
                make_uint2(pack_bf2(acc[r][0], acc[r][1]),
                           pack_bf2(acc[r][2], acc[r][3]));
            *(uint2*)&xhb[row * 64 + 32 + (c0 >> 1)] =
                make_uint2(pack_bf2(acc[r][4], acc[r][5]),
                           pack_bf2(acc[r][6], acc[r][7]));
        }
    }

    // logits from f32 accumulators
    const float4 as0 = *(const float4*)&att_src[c0];
    const float4 as1 = *(const float4*)&att_src[c0 + 64];
    const float4 ad0 = *(const float4*)&att_dst[c0];
    const float4 ad1 = *(const float4*)&att_dst[c0 + 64];
#pragma unroll
    for (int r = 0; r < 4; ++r) {
        float p0 = acc[r][0]*as0.x + acc[r][1]*as0.y + acc[r][2]*as0.z + acc[r][3]*as0.w;
        float p1 = acc[r][4]*as1.x + acc[r][5]*as1.y + acc[r][6]*as1.z + acc[r][7]*as1.w;
        float q0 = acc[r][0]*ad0.x + acc[r][1]*ad0.y + acc[r][2]*ad0.z + acc[r][3]*ad0.w;
        float q1 = acc[r][4]*ad1.x + acc[r][5]*ad1.y + acc[r][6]*ad1.z + acc[r][7]*ad1.w;
#pragma unroll
        for (int m = 1; m < 8; m <<= 1) {
            p0 += __shfl_xor(p0, m);
            p1 += __shfl_xor(p1, m);
            q0 += __shfl_xor(q0, m);
            q1 += __shfl_xor(q1, m);
        }
        const int row = row0 + r;
        if ((tx & 7) == 0 && row < n) {
            const int h = tx >> 3;
            asrc[row * 4 + h]     = p0;
            asrc[row * 4 + 2 + h] = p1;
            adst[row * 4 + h]     = q0;
            adst[row * 4 + 2 + h] = q1;
        }
    }
}

// ---------------------------------------------------------------------------
// P0: bucket counts via per-block LDS histogram (bucket = dst>>8).
// ---------------------------------------------------------------------------
__global__ __launch_bounds__(256) void p0_count_kernel(
    const int* __restrict__ dst, int* __restrict__ bucket_count, int E)
{
    __shared__ int h[KMAX];
    const int t = threadIdx.x;
    h[t] = 0; h[t + 256] = 0;
    __syncthreads();
    const int base = blockIdx.x * EPB;
#pragma unroll
    for (int i = 0; i < EPB / 256; ++i) {
        const int e = base + i * 256 + t;
        if (e < E) atomicAdd(&h[((uint)dst[e]) >> BSH], 1);
    }
    __syncthreads();
    if (h[t])       atomicAdd(&bucket_count[t],       h[t]);
    if (h[t + 256]) atomicAdd(&bucket_count[t + 256], h[t + 256]);
}

// ---------------------------------------------------------------------------
// P0scan: single-WG exclusive scan of 512 bucket counts.
// ---------------------------------------------------------------------------
__global__ __launch_bounds__(256) void p0_scan_kernel(
    const int* __restrict__ bucket_count, int* __restrict__ bucket_start,
    int* __restrict__ bucket_cursor)
{
    __shared__ int sd[256];
    const int t = threadIdx.x;
    const int a = bucket_count[2 * t], b = bucket_count[2 * t + 1];
    sd[t] = a + b;
    __syncthreads();
#pragma unroll
    for (int off = 1; off < 256; off <<= 1) {
        const int v = (t >= off) ? sd[t - off] : 0;
        __syncthreads();
        sd[t] += v;
        __syncthreads();
    }
    const int base = t ? sd[t - 1] : 0;
    bucket_start[2 * t]      = base;     bucket_cursor[2 * t]      = base;
    bucket_start[2 * t + 1]  = base + a; bucket_cursor[2 * t + 1]  = base + a;
}

// ---------------------------------------------------------------------------
// P1: partition edges into bucket-contiguous staging (src,dst pairs).
// Per-block LDS counting sort by bucket -> bucket-contiguous global writes.
// ---------------------------------------------------------------------------
__global__ __launch_bounds__(256) void p1_partition_kernel(
    const int* __restrict__ src, const int* __restrict__ dst,
    int* __restrict__ bucket_cursor, uint2* __restrict__ staged, int E)
{
    __shared__ int  hist[KMAX];
    __shared__ int  lbase[KMAX];
    __shared__ int  gbase[KMAX];
    __shared__ int  lcur[KMAX];
    __shared__ int  sd[256];
    __shared__ uint2 stage[EPB];   // 32 KiB
    const int t = threadIdx.x;
    hist[t] = 0; hist[t + 256] = 0;
    __syncthreads();

    const int base = blockIdx.x * EPB;
    uint sv[EPB / 256], dv[EPB / 256];
#pragma unroll
    for (int i = 0; i < EPB / 256; ++i) {
        const int e = base + i * 256 + t;
        if (e < E) {
            sv[i] = (uint)src[e];
            dv[i] = (uint)dst[e];
            atomicAdd(&hist[dv[i] >> BSH], 1);
        } else {
            dv[i] = 0xFFFFFFFFu;
        }
    }
    __syncthreads();

    // exclusive scan of hist[512]
    const int h0 = hist[2 * t], h1 = hist[2 * t + 1];
    sd[t] = h0 + h1;
    __syncthreads();
#pragma unroll
    for (int off = 1; off < 256; off <<= 1) {
        const int v = (t >= off) ? sd[t - off] : 0;
        __syncthreads();
        sd[t] += v;
        __syncthreads();
    }
    const int b2 = t ? sd[t - 1] : 0;
    lbase[2 * t]     = b2;      lcur[2 * t]     = b2;
    lbase[2 * t + 1] = b2 + h0; lcur[2 * t + 1] = b2 + h0;
    gbase[2 * t]     = h0 ? atomicAdd(&bucket_cursor[2 * t],     h0) : 0;
    gbase[2 * t + 1] = h1 ? atomicAdd(&bucket_cursor[2 * t + 1], h1) : 0;
    __syncthreads();

    // place edges into LDS staging, grouped by bucket
#pragma unroll
    for (int i = 0; i < EPB / 256; ++i) {
        if (dv[i] != 0xFFFFFFFFu) {
            const int slot = atomicAdd(&lcur[dv[i] >> BSH], 1);
            stage[slot] = make_uint2(sv[i], dv[i]);
        }
    }
    __syncthreads();

    // bucket-contiguous write-out
    const int total = sd[255];
    for (int j = t; j < total; j += 256) {
        const uint2 ev = stage[j];
        const int b = ev.y >> BSH;
        staged[gbase[b] + (j - lbase[b])] = ev;
    }
}

// ---------------------------------------------------------------------------
// P2: one WG per bucket. LDS counting sort by node -> coalesced csr_src write,
// plus node_beg / deg emitted directly (replaces global hist+scan+scatter).
// ---------------------------------------------------------------------------
__global__ __launch_bounds__(256) void p2_csr_kernel(
    const uint2* __restrict__ staged, const int* __restrict__ bucket_start,
    const int* __restrict__ bucket_count,
    int* __restrict__ csr_src, int* __restrict__ node_beg,
    int* __restrict__ deg_out, int n)
{
    __shared__ int deg[256];
    __shared__ int cur[256];
    __shared__ int sd[256];
    __shared__ int sorted[P2CAP];   // 32 KiB
    const int b  = blockIdx.x;
    const int t  = threadIdx.x;
    const int eb = bucket_start[b];
    const int cnt = min(bucket_count[b], P2CAP);
    const int v0 = b << BSH;

    deg[t] = 0;
    __syncthreads();
    for (int i = t; i < cnt; i += 256)
        atomicAdd(&deg[staged[eb + i].y & 255], 1);
    __syncthreads();

    const int d = deg[t];
    sd[t] = d;
    __syncthreads();
#pragma unroll
    for (int off = 1; off < 256; off <<= 1) {
        const int v = (t >= off) ? sd[t - off] : 0;
        __syncthreads();
        sd[t] += v;
        __syncthreads();
    }
    const int excl = t ? sd[t - 1] : 0;
    cur[t] = excl;
    if (v0 + t < n) {
        node_beg[v0 + t] = eb + excl;
        deg_out[v0 + t]  = d;
    }
    __syncthreads();

    for (int i = t; i < cnt; i += 256) {
        const uint2 ev = staged[eb + i];
        const int slot = atomicAdd(&cur[ev.y & 255], 1);
        sorted[slot] = (int)ev.x;
    }
    __syncthreads();

    for (int i = t; i < cnt; i += 256)
        csr_src[eb + i] = sorted[i];
}

// ---------------------------------------------------------------------------
// Fused aggregate v3: one wave per dst node, 4 edges per iteration.
//  - subgroup sub=lane>>4 owns edge e+sub; lane l16=lane&15 owns channels
//    [l16*8, l16*8+8) gathered as one uint4 (coalesced 256B per edge row)
//  - exp/logit-gather/loop overhead paid once per 4 edges
//  - all addressing 32-bit uint off SGPR bases
//  - epilogue: shfl_xor(16,32) cross-subgroup reduce, subgroup 0 writes row
// ---------------------------------------------------------------------------
__global__ __launch_bounds__(256) void aggregate_csr_kernel(
    const int* __restrict__ csr_src, const int* __restrict__ node_beg,
    const int* __restrict__ deg,
    const float* __restrict__ asrc, const float* __restrict__ adst,
    const uint* __restrict__ xhb, const float* __restrict__ bias,
    float* __restrict__ out, int n)
{
    const int node = blockIdx.x * 4 + (threadIdx.x >> 6);
    if (node >= n) return;
    const int  lane = threadIdx.x & 63;
    const int  sub  = lane >> 4;       // subgroup: which of 4 edges
    const uint l16  = lane & 15;       // lane within subgroup
    const uint h    = l16 >> 2;        // head 0..3
    const uint coff = l16 * 4u;        // uint offset of this lane's uint4

    const int beg = node_beg[node];
    const int end = beg + deg[node];

    const float adh = adst[(uint)node * 4u + h];

    // self-loop (subgroup 0 only; others contribute 0)
    const float zs = asrc[(uint)node * 4u + h] + adh;
    const float ws = (sub == 0) ? __expf(fmaxf(zs, NEG * zs)) : 0.f;
    const uint4 xs = *(const uint4*)&xhb[(uint)node * 64u + coff];
    float acc[8];
    acc[0] = ws * bf_lo(xs.x); acc[1] = ws * bf_hi(xs.x);
    acc[2] = ws * bf_lo(xs.y); acc[3] = ws * bf_hi(xs.y);
    acc[4] = ws * bf_lo(xs.z); acc[5] = ws * bf_hi(xs.z);
    acc[6] = ws * bf_lo(xs.w); acc[7] = ws * bf_hi(xs.w);
    float ssum = ws;

    for (int e = beg; e < end; e += 4) {
        const int  eg    = e + sub;
        const bool valid = eg < end;
        const uint s     = valid ? (uint)csr_src[eg] : (uint)node;
        const float z    = asrc[s * 4u + h] + adh;
        float w = __expf(fmaxf(z, NEG * z));
        w = valid ? w : 0.f;
        const uint4 xv = *(const uint4*)&xhb[s * 64u + coff];
        acc[0] = fmaf(w, bf_lo(xv.x), acc[0]);
        acc[1] = fmaf(w, bf_hi(xv.x), acc[1]);
        acc[2] = fmaf(w, bf_lo(xv.y), acc[2]);
        acc[3] = fmaf(w, bf_hi(xv.y), acc[3]);
        acc[4] = fmaf(w, bf_lo(xv.z), acc[4]);
        acc[5] = fmaf(w, bf_hi(xv.z), acc[5]);
        acc[6] = fmaf(w, bf_lo(xv.w), acc[6]);
        acc[7] = fmaf(w, bf_hi(xv.w), acc[7]);
        ssum += w;
    }

    // cross-subgroup reduction (4 partial sums at stride 16)
    ssum += __shfl_xor(ssum, 16);
    ssum += __shfl_xor(ssum, 32);
#pragma unroll
    for (int j = 0; j < 8; ++j) {
        acc[j] += __shfl_xor(acc[j], 16);
        acc[j] += __shfl_xor(acc[j], 32);
    }

    if (sub == 0) {
        const float inv = 1.f / ssum;
        const uint  c   = l16 * 8u;
        const float4 b0 = *(const float4*)&bias[c];
        const float4 b1 = *(const float4*)&bias[c + 4];
        float4 o0, o1;
        o0.x = fmaf(acc[0], inv, b0.x); o0.y = fmaf(acc[1], inv, b0.y);
        o0.z = fmaf(acc[2], inv, b0.z); o0.w = fmaf(acc[3], inv, b0.w);
        o1.x = fmaf(acc[4], inv, b1.x); o1.y = fmaf(acc[5], inv, b1.y);
        o1.z = fmaf(acc[6], inv, b1.z); o1.w = fmaf(acc[7], inv, b1.w);
        o0.x = fmaxf(o0.x, 0.f); o0.y = fmaxf(o0.y, 0.f);
        o0.z = fmaxf(o0.z, 0.f); o0.w = fmaxf(o0.w, 0.f);
        o1.x = fmaxf(o1.x, 0.f); o1.y = fmaxf(o1.y, 0.f);
        o1.z = fmaxf(o1.z, 0.f); o1.w = fmaxf(o1.w, 0.f);
        *(float4*)&out[(uint)node * 128u + c]      = o0;
        *(float4*)&out[(uint)node * 128u + c + 4u] = o1;
    }
}

// ---------------------------------------------------------------------------
extern "C" void kernel_launch(void* const* d_in, const int* in_sizes, int n_in,
                              void* d_out, int out_size, void* d_ws, size_t ws_size,
                              hipStream_t stream)
{
    const float* x       = (const float*)d_in[0];
    const int*   ei      = (const int*)d_in[1];   // [2,E] flat: src then dst
    const float* W       = (const float*)d_in[2];
    const float* att_src = (const float*)d_in[3];
    const float* att_dst = (const float*)d_in[4];
    const float* bias    = (const float*)d_in[5];

    const int n = in_sizes[0] / IN_C;
    const int E = in_sizes[1] / 2;
    const int* src = ei;
    const int* dst = ei + E;

    float* out = (float*)d_out;

    // workspace layout (all 4-byte units; staged offset is 8B-aligned for n even)
    uint*  xhb       = (uint*)d_ws;                        // n*64
    float* asrc      = (float*)(xhb + (size_t)n * 64);     // n*4
    float* adst      = asrc + (size_t)n * HEADS;           // n*4
    int*   node_beg  = (int*)(adst + (size_t)n * HEADS);   // n
    int*   deg       = node_beg + n;                       // n
    int*   bcount    = deg + n;                            // 512
    int*   bstart    = bcount + 512;                       // 512
    int*   bcursor   = bstart + 512;                       // 512
    uint2* staged    = (uint2*)(bcursor + 512);            // E pairs (8B each)
    int*   csr_src   = (int*)(staged + (size_t)E);         // E (+4 slack follows)

    const int K   = (n + 255) >> BSH;            // buckets
    const int NB  = (E + EPB - 1) / EPB;         // partition blocks

    hipMemsetAsync(bcount, 0, 512 * sizeof(int), stream);

    gemm_logits_kernel<<<(n + BM - 1) / BM, 512, 0, stream>>>(
        x, W, att_src, att_dst, xhb, asrc, adst, n);

    p0_count_kernel<<<NB, 256, 0, stream>>>(dst, bcount, E);
    p0_scan_kernel<<<1, 256, 0, stream>>>(bcount, bstart, bcursor);
    p1_partition_kernel<<<NB, 256, 0, stream>>>(src, dst, bcursor, staged, E);
    p2_csr_kernel<<<K, 256, 0, stream>>>(staged, bstart, bcount,
                                         csr_src, node_beg, deg, n);
    aggregate_csr_kernel<<<(n + 3) / 4, 256, 0, stream>>>(csr_src, node_beg, deg,
                                                          asrc, adst, xhb, bias,
                                                          out, n);
}

// Round 8
// 206.559 us; speedup vs baseline: 10.2363x; 1.0283x over previous
//
#include <hip/hip_runtime.h>

#define IN_C   128
#define HC     128   // HEADS*OUT_C
#define HEADS  4
#define NEG    0.2f
#define BM     128   // rows per block in GEMM (512 threads)

#define BSH    8     // bucket = dst >> 8  (256 nodes per bucket)
#define KMAX   512   // max buckets (n <= 131072)
#define EPB    4096  // edges per partition block
#define P2CAP  8192  // LDS sort capacity per bucket (mean 4096, sigma 64)

// bf16 helpers: xh stored packed, 2 channels per uint (ch 2j = low 16 bits).
__device__ __forceinline__ uint bf16_rne(float f) {
    uint u = __float_as_uint(f);
    return (u + 0x7FFFu + ((u >> 16) & 1u)) >> 16;
}
__device__ __forceinline__ uint pack_bf2(float even, float odd) {
    return bf16_rne(even) | (bf16_rne(odd) << 16);
}
__device__ __forceinline__ float bf_lo(uint u) { return __uint_as_float(u << 16); }
__device__ __forceinline__ float bf_hi(uint u) { return __uint_as_float(u & 0xFFFF0000u); }

// ---------------------------------------------------------------------------
// Pass A: xh = x @ W (output packed bf16), plus per-node logits from the f32
// accumulators. Block = 512 threads, 128 rows; thread owns 4 rows x 8 cols.
// ---------------------------------------------------------------------------
__global__ __launch_bounds__(512) void gemm_logits_kernel(
    const float* __restrict__ x, const float* __restrict__ W,
    const float* __restrict__ att_src, const float* __restrict__ att_dst,
    uint* __restrict__ xhb, float* __restrict__ asrc, float* __restrict__ adst,
    int n)
{
    __shared__ float Wl[IN_C * HC];   // 64 KiB
    const int tid = threadIdx.x;
#pragma unroll
    for (int i = 0; i < 8; ++i) {
        const int idx = (i * 512 + tid) * 4;
        *(float4*)&Wl[idx] = *(const float4*)&W[idx];
    }

    const int tx   = tid & 15;
    const int ty   = tid >> 4;        // 0..31
    const int c0   = tx * 4;
    const int row0 = blockIdx.x * BM + ty * 4;

    __syncthreads();

    float acc[4][8];
#pragma unroll
    for (int r = 0; r < 4; ++r)
#pragma unroll
        for (int j = 0; j < 8; ++j) acc[r][j] = 0.f;

    float4 xq[4];
#pragma unroll
    for (int r = 0; r < 4; ++r)
        xq[r] = (row0 + r < n) ? *(const float4*)&x[(size_t)(row0 + r) * IN_C]
                               : make_float4(0.f, 0.f, 0.f, 0.f);

    for (int kc = 0; kc < 32; ++kc) {
        const int k = kc * 4;
        float4 xn[4];
#pragma unroll
        for (int r = 0; r < 4; ++r)
            xn[r] = (kc < 31 && row0 + r < n)
                  ? *(const float4*)&x[(size_t)(row0 + r) * IN_C + k + 4]
                  : make_float4(0.f, 0.f, 0.f, 0.f);
#pragma unroll
        for (int kk = 0; kk < 4; ++kk) {
            const float4 w0 = *(const float4*)&Wl[(k + kk) * HC + c0];
            const float4 w1 = *(const float4*)&Wl[(k + kk) * HC + c0 + 64];
#pragma unroll
            for (int r = 0; r < 4; ++r) {
                const float xv = ((const float*)&xq[r])[kk];
                acc[r][0] = fmaf(xv, w0.x, acc[r][0]);
                acc[r][1] = fmaf(xv, w0.y, acc[r][1]);
                acc[r][2] = fmaf(xv, w0.z, acc[r][2]);
                acc[r][3] = fmaf(xv, w0.w, acc[r][3]);
                acc[r][4] = fmaf(xv, w1.x, acc[r][4]);
                acc[r][5] = fmaf(xv, w1.y, acc[r][5]);
                acc[r][6] = fmaf(xv, w1.z, acc[r][6]);
                acc[r][7] = fmaf(xv, w1.w, acc[r][7]);
            }
        }
#pragma unroll
        for (int r = 0; r < 4; ++r) xq[r] = xn[r];
    }

    // store xh (packed bf16): uint index = row*64 + c/2
#pragma unroll
    for (int r = 0; r < 4; ++r) {
        const int row = row0 + r;
        if (row < n) {
            *(uint2*)&xhb[row * 64 + (c0 >> 1)] =
                make_uint2(pack_bf2(acc[r][0], acc[r][1]),
                           pack_bf2(acc[r][2], acc[r][3]));
            *(uint2*)&xhb[row * 64 + 32 + (c0 >> 1)] =
                make_uint2(pack_bf2(acc[r][4], acc[r][5]),
                           pack_bf2(acc[r][6], acc[r][7]));
        }
    }

    // logits from f32 accumulators
    const float4 as0 = *(const float4*)&att_src[c0];
    const float4 as1 = *(const float4*)&att_src[c0 + 64];
    const float4 ad0 = *(const float4*)&att_dst[c0];
    const float4 ad1 = *(const float4*)&att_dst[c0 + 64];
#pragma unroll
    for (int r = 0; r < 4; ++r) {
        float p0 = acc[r][0]*as0.x + acc[r][1]*as0.y + acc[r][2]*as0.z + acc[r][3]*as0.w;
        float p1 = acc[r][4]*as1.x + acc[r][5]*as1.y + acc[r][6]*as1.z + acc[r][7]*as1.w;
        float q0 = acc[r][0]*ad0.x + acc[r][1]*ad0.y + acc[r][2]*ad0.z + acc[r][3]*ad0.w;
        float q1 = acc[r][4]*ad1.x + acc[r][5]*ad1.y + acc[r][6]*ad1.z + acc[r][7]*ad1.w;
#pragma unroll
        for (int m = 1; m < 8; m <<= 1) {
            p0 += __shfl_xor(p0, m);
            p1 += __shfl_xor(p1, m);
            q0 += __shfl_xor(q0, m);
            q1 += __shfl_xor(q1, m);
        }
        const int row = row0 + r;
        if ((tx & 7) == 0 && row < n) {
            const int h = tx >> 3;
            asrc[row * 4 + h]     = p0;
            asrc[row * 4 + 2 + h] = p1;
            adst[row * 4 + h]     = q0;
            adst[row * 4 + 2 + h] = q1;
        }
    }
}

// ---------------------------------------------------------------------------
// P0: bucket counts via per-block LDS histogram (bucket = dst>>8).
// ---------------------------------------------------------------------------
__global__ __launch_bounds__(256) void p0_count_kernel(
    const int* __restrict__ dst, int* __restrict__ bucket_count, int E)
{
    __shared__ int h[KMAX];
    const int t = threadIdx.x;
    h[t] = 0; h[t + 256] = 0;
    __syncthreads();
    const int base = blockIdx.x * EPB;
#pragma unroll
    for (int i = 0; i < EPB / 256; ++i) {
        const int e = base + i * 256 + t;
        if (e < E) atomicAdd(&h[((uint)dst[e]) >> BSH], 1);
    }
    __syncthreads();
    if (h[t])       atomicAdd(&bucket_count[t],       h[t]);
    if (h[t + 256]) atomicAdd(&bucket_count[t + 256], h[t + 256]);
}

// ---------------------------------------------------------------------------
// P0scan: single-WG exclusive scan of 512 bucket counts.
// ---------------------------------------------------------------------------
__global__ __launch_bounds__(256) void p0_scan_kernel(
    const int* __restrict__ bucket_count, int* __restrict__ bucket_start,
    int* __restrict__ bucket_cursor)
{
    __shared__ int sd[256];
    const int t = threadIdx.x;
    const int a = bucket_count[2 * t], b = bucket_count[2 * t + 1];
    sd[t] = a + b;
    __syncthreads();
#pragma unroll
    for (int off = 1; off < 256; off <<= 1) {
        const int v = (t >= off) ? sd[t - off] : 0;
        __syncthreads();
        sd[t] += v;
        __syncthreads();
    }
    const int base = t ? sd[t - 1] : 0;
    bucket_start[2 * t]      = base;     bucket_cursor[2 * t]      = base;
    bucket_start[2 * t + 1]  = base + a; bucket_cursor[2 * t + 1]  = base + a;
}

// ---------------------------------------------------------------------------
// P1: partition edges into bucket-contiguous staging (src,dst pairs).
// ---------------------------------------------------------------------------
__global__ __launch_bounds__(256) void p1_partition_kernel(
    const int* __restrict__ src, const int* __restrict__ dst,
    int* __restrict__ bucket_cursor, uint2* __restrict__ staged, int E)
{
    __shared__ int  hist[KMAX];
    __shared__ int  lbase[KMAX];
    __shared__ int  gbase[KMAX];
    __shared__ int  lcur[KMAX];
    __shared__ int  sd[256];
    __shared__ uint2 stage[EPB];   // 32 KiB
    const int t = threadIdx.x;
    hist[t] = 0; hist[t + 256] = 0;
    __syncthreads();

    const int base = blockIdx.x * EPB;
    uint sv[EPB / 256], dv[EPB / 256];
#pragma unroll
    for (int i = 0; i < EPB / 256; ++i) {
        const int e = base + i * 256 + t;
        if (e < E) {
            sv[i] = (uint)src[e];
            dv[i] = (uint)dst[e];
            atomicAdd(&hist[dv[i] >> BSH], 1);
        } else {
            dv[i] = 0xFFFFFFFFu;
        }
    }
    __syncthreads();

    // exclusive scan of hist[512]
    const int h0 = hist[2 * t], h1 = hist[2 * t + 1];
    sd[t] = h0 + h1;
    __syncthreads();
#pragma unroll
    for (int off = 1; off < 256; off <<= 1) {
        const int v = (t >= off) ? sd[t - off] : 0;
        __syncthreads();
        sd[t] += v;
        __syncthreads();
    }
    const int b2 = t ? sd[t - 1] : 0;
    lbase[2 * t]     = b2;      lcur[2 * t]     = b2;
    lbase[2 * t + 1] = b2 + h0; lcur[2 * t + 1] = b2 + h0;
    gbase[2 * t]     = h0 ? atomicAdd(&bucket_cursor[2 * t],     h0) : 0;
    gbase[2 * t + 1] = h1 ? atomicAdd(&bucket_cursor[2 * t + 1], h1) : 0;
    __syncthreads();

    // place edges into LDS staging, grouped by bucket
#pragma unroll
    for (int i = 0; i < EPB / 256; ++i) {
        if (dv[i] != 0xFFFFFFFFu) {
            const int slot = atomicAdd(&lcur[dv[i] >> BSH], 1);
            stage[slot] = make_uint2(sv[i], dv[i]);
        }
    }
    __syncthreads();

    // bucket-contiguous write-out
    const int total = sd[255];
    for (int j = t; j < total; j += 256) {
        const uint2 ev = stage[j];
        const int b = ev.y >> BSH;
        staged[gbase[b] + (j - lbase[b])] = ev;
    }
}

// ---------------------------------------------------------------------------
// P2: one WG per bucket. LDS counting sort by node -> coalesced csr_src write,
// plus node_beg / deg emitted directly.
// ---------------------------------------------------------------------------
__global__ __launch_bounds__(256) void p2_csr_kernel(
    const uint2* __restrict__ staged, const int* __restrict__ bucket_start,
    const int* __restrict__ bucket_count,
    int* __restrict__ csr_src, int* __restrict__ node_beg,
    int* __restrict__ deg_out, int n)
{
    __shared__ int deg[256];
    __shared__ int cur[256];
    __shared__ int sd[256];
    __shared__ int sorted[P2CAP];   // 32 KiB
    const int b  = blockIdx.x;
    const int t  = threadIdx.x;
    const int eb = bucket_start[b];
    const int cnt = min(bucket_count[b], P2CAP);
    const int v0 = b << BSH;

    deg[t] = 0;
    __syncthreads();
    for (int i = t; i < cnt; i += 256)
        atomicAdd(&deg[staged[eb + i].y & 255], 1);
    __syncthreads();

    const int d = deg[t];
    sd[t] = d;
    __syncthreads();
#pragma unroll
    for (int off = 1; off < 256; off <<= 1) {
        const int v = (t >= off) ? sd[t - off] : 0;
        __syncthreads();
        sd[t] += v;
        __syncthreads();
    }
    const int excl = t ? sd[t - 1] : 0;
    cur[t] = excl;
    if (v0 + t < n) {
        node_beg[v0 + t] = eb + excl;
        deg_out[v0 + t]  = d;
    }
    __syncthreads();

    for (int i = t; i < cnt; i += 256) {
        const uint2 ev = staged[eb + i];
        const int slot = atomicAdd(&cur[ev.y & 255], 1);
        sorted[slot] = (int)ev.x;
    }
    __syncthreads();

    for (int i = t; i < cnt; i += 256)
        csr_src[eb + i] = sorted[i];
}

// ---------------------------------------------------------------------------
// Fused aggregate v4: one wave per dst node, 4 edges/iter, SOFTWARE-PIPELINED
// 2 deep: next chunk's indices + gathers (asrc, xhb) issued BEFORE consuming
// the current chunk -> 8 edges (2x256B rows) in flight per wave.
// Tail chunks clamp to the node's own (L1-hot) row with weight zeroed.
// ---------------------------------------------------------------------------
__global__ __launch_bounds__(256) void aggregate_csr_kernel(
    const int* __restrict__ csr_src, const int* __restrict__ node_beg,
    const int* __restrict__ deg,
    const float* __restrict__ asrc, const float* __restrict__ adst,
    const uint* __restrict__ xhb, const float* __restrict__ bias,
    float* __restrict__ out, int n)
{
    const int node = blockIdx.x * 4 + (threadIdx.x >> 6);
    if (node >= n) return;
    const int  lane = threadIdx.x & 63;
    const int  sub  = lane >> 4;       // subgroup: which of 4 edges
    const uint l16  = lane & 15;       // lane within subgroup
    const uint h    = l16 >> 2;        // head 0..3
    const uint coff = l16 * 4u;        // uint offset of this lane's uint4

    const int beg = node_beg[node];
    const int end = beg + deg[node];

    const float adh = adst[(uint)node * 4u + h];

    // self-loop (subgroup 0 only; others contribute 0)
    const float zs = asrc[(uint)node * 4u + h] + adh;
    const float ws = (sub == 0) ? __expf(fmaxf(zs, NEG * zs)) : 0.f;
    const uint4 xs = *(const uint4*)&xhb[(uint)node * 64u + coff];
    float acc[8];
    acc[0] = ws * bf_lo(xs.x); acc[1] = ws * bf_hi(xs.x);
    acc[2] = ws * bf_lo(xs.y); acc[3] = ws * bf_hi(xs.y);
    acc[4] = ws * bf_lo(xs.z); acc[5] = ws * bf_hi(xs.z);
    acc[6] = ws * bf_lo(xs.w); acc[7] = ws * bf_hi(xs.w);
    float ssum = ws;

    if (beg < end) {
        // ---- prologue: stage 0 loads ----
        int  eg0 = beg + sub;
        bool v0  = eg0 < end;
        uint s0  = v0 ? (uint)csr_src[eg0] : (uint)node;
        float a0 = asrc[s0 * 4u + h];
        uint4 x0 = *(const uint4*)&xhb[s0 * 64u + coff];

        for (int e = beg; e < end; e += 4) {
            // ---- issue stage 1 (next chunk) loads first ----
            const int  eg1 = e + 4 + sub;
            const bool v1  = eg1 < end;
            const uint s1  = v1 ? (uint)csr_src[eg1] : (uint)node;
            const float a1 = asrc[s1 * 4u + h];
            const uint4 x1 = *(const uint4*)&xhb[s1 * 64u + coff];

            // ---- consume stage 0 ----
            const float z = a0 + adh;
            float w = __expf(fmaxf(z, NEG * z));
            w = v0 ? w : 0.f;
            acc[0] = fmaf(w, bf_lo(x0.x), acc[0]);
            acc[1] = fmaf(w, bf_hi(x0.x), acc[1]);
            acc[2] = fmaf(w, bf_lo(x0.y), acc[2]);
            acc[3] = fmaf(w, bf_hi(x0.y), acc[3]);
            acc[4] = fmaf(w, bf_lo(x0.z), acc[4]);
            acc[5] = fmaf(w, bf_hi(x0.z), acc[5]);
            acc[6] = fmaf(w, bf_lo(x0.w), acc[6]);
            acc[7] = fmaf(w, bf_hi(x0.w), acc[7]);
            ssum += w;

            v0 = v1; a0 = a1; x0 = x1;
        }
    }

    // cross-subgroup reduction (4 partial sums at stride 16)
    ssum += __shfl_xor(ssum, 16);
    ssum += __shfl_xor(ssum, 32);
#pragma unroll
    for (int j = 0; j < 8; ++j) {
        acc[j] += __shfl_xor(acc[j], 16);
        acc[j] += __shfl_xor(acc[j], 32);
    }

    if (sub == 0) {
        const float inv = 1.f / ssum;
        const uint  c   = l16 * 8u;
        const float4 b0 = *(const float4*)&bias[c];
        const float4 b1 = *(const float4*)&bias[c + 4];
        float4 o0, o1;
        o0.x = fmaf(acc[0], inv, b0.x); o0.y = fmaf(acc[1], inv, b0.y);
        o0.z = fmaf(acc[2], inv, b0.z); o0.w = fmaf(acc[3], inv, b0.w);
        o1.x = fmaf(acc[4], inv, b1.x); o1.y = fmaf(acc[5], inv, b1.y);
        o1.z = fmaf(acc[6], inv, b1.z); o1.w = fmaf(acc[7], inv, b1.w);
        o0.x = fmaxf(o0.x, 0.f); o0.y = fmaxf(o0.y, 0.f);
        o0.z = fmaxf(o0.z, 0.f); o0.w = fmaxf(o0.w, 0.f);
        o1.x = fmaxf(o1.x, 0.f); o1.y = fmaxf(o1.y, 0.f);
        o1.z = fmaxf(o1.z, 0.f); o1.w = fmaxf(o1.w, 0.f);
        *(float4*)&out[(uint)node * 128u + c]      = o0;
        *(float4*)&out[(uint)node * 128u + c + 4u] = o1;
    }
}

// ---------------------------------------------------------------------------
extern "C" void kernel_launch(void* const* d_in, const int* in_sizes, int n_in,
                              void* d_out, int out_size, void* d_ws, size_t ws_size,
                              hipStream_t stream)
{
    const float* x       = (const float*)d_in[0];
    const int*   ei      = (const int*)d_in[1];   // [2,E] flat: src then dst
    const float* W       = (const float*)d_in[2];
    const float* att_src = (const float*)d_in[3];
    const float* att_dst = (const float*)d_in[4];
    const float* bias    = (const float*)d_in[5];

    const int n = in_sizes[0] / IN_C;
    const int E = in_sizes[1] / 2;
    const int* src = ei;
    const int* dst = ei + E;

    float* out = (float*)d_out;

    // workspace layout (all 4-byte units; staged offset is 8B-aligned for n even)
    uint*  xhb       = (uint*)d_ws;                        // n*64
    float* asrc      = (float*)(xhb + (size_t)n * 64);     // n*4
    float* adst      = asrc + (size_t)n * HEADS;           // n*4
    int*   node_beg  = (int*)(adst + (size_t)n * HEADS);   // n
    int*   deg       = node_beg + n;                       // n
    int*   bcount    = deg + n;                            // 512
    int*   bstart    = bcount + 512;                       // 512
    int*   bcursor   = bstart + 512;                       // 512
    uint2* staged    = (uint2*)(bcursor + 512);            // E pairs (8B each)
    int*   csr_src   = (int*)(staged + (size_t)E);         // E (+4 slack follows)

    const int K   = (n + 255) >> BSH;            // buckets
    const int NB  = (E + EPB - 1) / EPB;         // partition blocks

    hipMemsetAsync(bcount, 0, 512 * sizeof(int), stream);

    gemm_logits_kernel<<<(n + BM - 1) / BM, 512, 0, stream>>>(
        x, W, att_src, att_dst, xhb, asrc, adst, n);

    p0_count_kernel<<<NB, 256, 0, stream>>>(dst, bcount, E);
    p0_scan_kernel<<<1, 256, 0, stream>>>(bcount, bstart, bcursor);
    p1_partition_kernel<<<NB, 256, 0, stream>>>(src, dst, bcursor, staged, E);
    p2_csr_kernel<<<K, 256, 0, stream>>>(staged, bstart, bcount,
                                         csr_src, node_beg, deg, n);
    aggregate_csr_kernel<<<(n + 3) / 4, 256, 0, stream>>>(csr_src, node_beg, deg,
                                                          asrc, adst, xhb, bias,
                                                          out, n);
}